// Round 1
// 622.312 us; speedup vs baseline: 1.0426x; 1.0426x over previous
//
#include <hip/hip_runtime.h>

#define KITER 10
typedef unsigned short bf16_t;
typedef __attribute__((ext_vector_type(4))) short bf16x4;
typedef __attribute__((ext_vector_type(8))) short bf16x8;
typedef __attribute__((ext_vector_type(4))) float f32x4;

__device__ __forceinline__ float bf2f(bf16_t u) {
  union { unsigned u; float f; } cv;
  cv.u = ((unsigned)u) << 16;
  return cv.f;
}
__device__ __forceinline__ bf16_t f2bf(float f) {
  unsigned u = __float_as_uint(f);
  unsigned r = (u + 0x7FFFu + ((u >> 16) & 1u)) >> 16;  // round-nearest-even
  return (bf16_t)r;
}

// ---------------- setup kernels ----------------

__global__ void k_zero(int* __restrict__ p, int n) {
  int i = blockIdx.x * blockDim.x + threadIdx.x;
  if (i < n) p[i] = 0;
}

__global__ void k_count(const int* __restrict__ col, int* __restrict__ cnt, int E) {
  int e = blockIdx.x * blockDim.x + threadIdx.x;
  if (e < E) atomicAdd(&cnt[col[e]], 1);
}

__global__ void k_blocksum(const int* __restrict__ cnt, int* __restrict__ bsum, int N) {
  __shared__ int s[256];
  int tid = threadIdx.x;
  int i = blockIdx.x * 256 + tid;
  s[tid] = (i < N) ? cnt[i] : 0;
  __syncthreads();
  for (int off = 128; off > 0; off >>= 1) {
    if (tid < off) s[tid] += s[tid + off];
    __syncthreads();
  }
  if (tid == 0) bsum[blockIdx.x] = s[0];
}

// single block of 512 threads: exclusive scan of bsum (NB <= 512)
__global__ void k_scanbsum(int* __restrict__ bsum, int NB, int* __restrict__ rowptr,
                           int N, int E) {
  __shared__ int s[512];
  int tid = threadIdx.x;
  int v = (tid < NB) ? bsum[tid] : 0;
  s[tid] = v;
  __syncthreads();
  for (int off = 1; off < 512; off <<= 1) {
    int t = (tid >= off) ? s[tid - off] : 0;
    __syncthreads();
    s[tid] += t;
    __syncthreads();
  }
  if (tid < NB) bsum[tid] = s[tid] - v;  // exclusive block offsets
  if (tid == 0) rowptr[N] = E;
}

__global__ void k_scan(const int* __restrict__ cnt, const int* __restrict__ bsum,
                       int* __restrict__ rowptr, int* __restrict__ cursor,
                       float* __restrict__ dinv, float* __restrict__ selfw, int N) {
  __shared__ int s[256];
  int tid = threadIdx.x;
  int i = blockIdx.x * 256 + tid;
  int v = (i < N) ? cnt[i] : 0;
  s[tid] = v;
  __syncthreads();
  for (int off = 1; off < 256; off <<= 1) {
    int t = (tid >= off) ? s[tid - off] : 0;
    __syncthreads();
    s[tid] += t;
    __syncthreads();
  }
  if (i < N) {
    int excl = s[tid] - v + bsum[blockIdx.x];
    rowptr[i] = excl;
    cursor[i] = excl;
    float dg = (float)v + 1.0f;  // deg includes self-loop
    dinv[i] = rsqrtf(dg);
    selfw[i] = 0.9f / dg;  // 0.9 * dinv^2
  }
}

__global__ void k_scatter(const int* __restrict__ ei, int E,
                          const float* __restrict__ dinv, int* __restrict__ cursor,
                          int2* __restrict__ ed) {
  int e = blockIdx.x * blockDim.x + threadIdx.x;
  if (e >= E) return;
  int s = ei[e];       // source
  int c = ei[E + e];   // target
  int slot = atomicAdd(&cursor[c], 1);
  ed[slot] = make_int2(s, __float_as_int(0.9f * dinv[s] * dinv[c]));
}

// ---------------- W pack: split fp32 W into bf16 hi/lo, MFMA B-frag layout ----
// layout: [kc=8][cg=4][lane=64][j=8], value = W[kc*32 + (lane>>4)*8 + j][cg*16 + (lane&15)]
__global__ void k_prep_w(const float* __restrict__ W, short* __restrict__ Whp,
                         short* __restrict__ Wlp) {
  int i = blockIdx.x * 256 + threadIdx.x;  // 0..16383
  int j = i & 7;
  int lane = (i >> 3) & 63;
  int cg = (i >> 9) & 3;
  int kc = i >> 11;
  int k = kc * 32 + (lane >> 4) * 8 + j;
  int col = cg * 16 + (lane & 15);
  float w = W[k * 64 + col];
  unsigned u = __float_as_uint(w);
  unsigned hbits = u & 0xFFFF0000u;  // truncate: residual captured exactly by lo
  Whp[i] = (short)(hbits >> 16);
  Wlp[i] = (short)f2bf(w - __uint_as_float(hbits));
}

// ---------------- h = relu(x @ W1 + b1) via split-precision bf16 MFMA --------
// 512 threads = 8 waves; each wave one 16-row tile; K=256 as 8 chunks of 32.
// h = xh@Wh + xl@Wh + xh@Wl  (error ~2^-17 relative)
__global__ __launch_bounds__(512) void k_gemm_mfma(const float* __restrict__ x,
                                                   const short* __restrict__ Whp,
                                                   const short* __restrict__ Wlp,
                                                   const float* __restrict__ b,
                                                   float* __restrict__ h,
                                                   bf16_t* __restrict__ hb, int N) {
  __shared__ short WhS[16384];  // 32 KB
  __shared__ short WlS[16384];  // 32 KB
  int tid = threadIdx.x;
  for (int i = tid; i < 2048; i += 512) {
    ((int4*)WhS)[i] = ((const int4*)Whp)[i];
    ((int4*)WlS)[i] = ((const int4*)Wlp)[i];
  }
  __syncthreads();
  int wid = tid >> 6;
  int lane = tid & 63;
  int row0 = (blockIdx.x * 8 + wid) * 16;
  if (row0 >= N) return;
  int arow = row0 + (lane & 15);
  if (arow >= N) arow = N - 1;  // clamp (stores guarded)
  const float* xr = x + (size_t)arow * 256 + (lane >> 4) * 8;

  // prefetch whole row slice: 8 kchunks x 8 floats
  f32x4 xa[8], xb[8];
#pragma unroll
  for (int kc = 0; kc < 8; ++kc) {
    xa[kc] = *(const f32x4*)(xr + kc * 32);
    xb[kc] = *(const f32x4*)(xr + kc * 32 + 4);
  }

  f32x4 acc[4];
#pragma unroll
  for (int cg = 0; cg < 4; ++cg) acc[cg] = (f32x4){0.f, 0.f, 0.f, 0.f};

#pragma unroll
  for (int kc = 0; kc < 8; ++kc) {
    // split x into bf16 hi (truncate) + lo (RNE of residual)
    float f[8] = {xa[kc].x, xa[kc].y, xa[kc].z, xa[kc].w,
                  xb[kc].x, xb[kc].y, xb[kc].z, xb[kc].w};
    bf16x8 xh, xl;
#pragma unroll
    for (int j = 0; j < 8; ++j) {
      unsigned u = __float_as_uint(f[j]);
      unsigned hbits = u & 0xFFFF0000u;
      xh[j] = (short)(hbits >> 16);
      xl[j] = (short)f2bf(f[j] - __uint_as_float(hbits));
    }
#pragma unroll
    for (int cg = 0; cg < 4; ++cg) {
      const bf16x8 wh = *(const bf16x8*)&WhS[((kc * 4 + cg) * 64 + lane) * 8];
      const bf16x8 wl = *(const bf16x8*)&WlS[((kc * 4 + cg) * 64 + lane) * 8];
      acc[cg] = __builtin_amdgcn_mfma_f32_16x16x32_bf16(xh, wh, acc[cg], 0, 0, 0);
      acc[cg] = __builtin_amdgcn_mfma_f32_16x16x32_bf16(xl, wh, acc[cg], 0, 0, 0);
      acc[cg] = __builtin_amdgcn_mfma_f32_16x16x32_bf16(xh, wl, acc[cg], 0, 0, 0);
    }
  }

  // epilogue: C/D layout col=lane&15 (within cg), row=row0+(lane>>4)*4+r
  int rbase = row0 + (lane >> 4) * 4;
#pragma unroll
  for (int cg = 0; cg < 4; ++cg) {
    int col = cg * 16 + (lane & 15);
    float bias = b[col];
#pragma unroll
    for (int r = 0; r < 4; ++r) {
      int row = rbase + r;
      if (row < N) {
        float v = fmaxf(acc[cg][r] + bias, 0.f);
        size_t o = (size_t)row * 64 + col;
        h[o] = v;
        hb[o] = f2bf(v);
      }
    }
  }
}

// ---------------- propagation v2: 16 lanes per node, 4 nodes per wave --------
// lane = (g = lane>>4 node sub-index, u = lane&15 channel quartet).
// Per edge: one 8B bf16x4 gather per lane (16 lanes cover the 128B z-row in
// one instruction vs 16 scalar ushort loads before), one 8B ed load
// (broadcast within the 16-lane group), 4 FMAs. No cross-lane reduce.
// Self/h/store traffic perfectly coalesced (nodes consecutive within wave).
template <int LAST>
__global__ __launch_bounds__(256) void k_prop(const int* __restrict__ rowptr,
                                              const int2* __restrict__ ed,
                                              const float* __restrict__ selfw,
                                              const bf16_t* __restrict__ zin,
                                              const bf16_t* __restrict__ hbi,
                                              const float* __restrict__ hf,
                                              void* __restrict__ zout_, int N) {
  int tid = threadIdx.x;
  int lane = tid & 63;
  int u = lane & 15;  // channel quartet: channels u*4 .. u*4+3
  int g = lane >> 4;  // node sub-index within wave (0..3)
  int node = blockIdx.x * 16 + (tid >> 6) * 4 + g;
  bool live = node < N;
  if (!live) node = N - 1;  // clamp; stores guarded
  int beg = rowptr[node];
  int end = rowptr[node + 1];
  size_t base = (size_t)node * 64 + u * 4;

  // self-loop term
  float sw = selfw[node];
  union U { bf16x4 v; unsigned d[2]; };
  U zs;
  zs.v = *(const bf16x4*)(zin + base);
  float acc0 = sw * __uint_as_float(zs.d[0] << 16);
  float acc1 = sw * __uint_as_float(zs.d[0] & 0xFFFF0000u);
  float acc2 = sw * __uint_as_float(zs.d[1] << 16);
  float acc3 = sw * __uint_as_float(zs.d[1] & 0xFFFF0000u);

  int e = beg;
  while (e + 1 < end) {
    int2 q0 = ed[e];
    int2 q1 = ed[e + 1];
    U z0, z1;
    z0.v = *(const bf16x4*)(zin + (size_t)q0.x * 64 + u * 4);
    z1.v = *(const bf16x4*)(zin + (size_t)q1.x * 64 + u * 4);
    float w0 = __int_as_float(q0.y);
    float w1 = __int_as_float(q1.y);
    acc0 += w0 * __uint_as_float(z0.d[0] << 16);
    acc1 += w0 * __uint_as_float(z0.d[0] & 0xFFFF0000u);
    acc2 += w0 * __uint_as_float(z0.d[1] << 16);
    acc3 += w0 * __uint_as_float(z0.d[1] & 0xFFFF0000u);
    acc0 += w1 * __uint_as_float(z1.d[0] << 16);
    acc1 += w1 * __uint_as_float(z1.d[0] & 0xFFFF0000u);
    acc2 += w1 * __uint_as_float(z1.d[1] << 16);
    acc3 += w1 * __uint_as_float(z1.d[1] & 0xFFFF0000u);
    e += 2;
  }
  if (e < end) {
    int2 q = ed[e];
    U z0;
    z0.v = *(const bf16x4*)(zin + (size_t)q.x * 64 + u * 4);
    float w = __int_as_float(q.y);
    acc0 += w * __uint_as_float(z0.d[0] << 16);
    acc1 += w * __uint_as_float(z0.d[0] & 0xFFFF0000u);
    acc2 += w * __uint_as_float(z0.d[1] << 16);
    acc3 += w * __uint_as_float(z0.d[1] & 0xFFFF0000u);
  }

  if (LAST) {
    f32x4 hv = *(const f32x4*)(hf + base);
    f32x4 res;
    res.x = acc0 + 0.1f * hv.x;
    res.y = acc1 + 0.1f * hv.y;
    res.z = acc2 + 0.1f * hv.z;
    res.w = acc3 + 0.1f * hv.w;
    if (live) *(f32x4*)((float*)zout_ + base) = res;
  } else {
    U hv;
    hv.v = *(const bf16x4*)(hbi + base);
    float r0 = acc0 + 0.1f * __uint_as_float(hv.d[0] << 16);
    float r1 = acc1 + 0.1f * __uint_as_float(hv.d[0] & 0xFFFF0000u);
    float r2 = acc2 + 0.1f * __uint_as_float(hv.d[1] << 16);
    float r3 = acc3 + 0.1f * __uint_as_float(hv.d[1] & 0xFFFF0000u);
    unsigned o0 = (unsigned)f2bf(r0) | (((unsigned)f2bf(r1)) << 16);
    unsigned o1 = (unsigned)f2bf(r2) | (((unsigned)f2bf(r3)) << 16);
    if (live) {
      uint2 o = make_uint2(o0, o1);
      *(uint2*)((bf16_t*)zout_ + base) = o;
    }
  }
}

// ---------------- launch ----------------

extern "C" void kernel_launch(void* const* d_in, const int* in_sizes, int n_in,
                              void* d_out, int out_size, void* d_ws, size_t ws_size,
                              hipStream_t stream) {
  const float* x = (const float*)d_in[0];
  const int* ei = (const int*)d_in[1];  // int32 per harness contract
  const float* W1 = (const float*)d_in[2];
  const float* b1 = (const float*)d_in[3];
  float* zfinal = (float*)d_out;

  int OUT = in_sizes[3];        // 64
  int IN = in_sizes[2] / OUT;   // 256
  int N = in_sizes[0] / IN;     // 100000
  int E = in_sizes[1] / 2;      // 1600000

  char* ws = (char*)d_ws;
  size_t off = 0;
  auto alloc = [&](size_t bytes) -> char* {
    char* p = ws + off;
    off = (off + bytes + 255) & ~(size_t)255;
    return p;
  };
  float* h = (float*)alloc((size_t)N * OUT * 4);     // 25.6 MB
  bf16_t* hb = (bf16_t*)alloc((size_t)N * OUT * 2);  // 12.8 MB
  bf16_t* z0 = (bf16_t*)alloc((size_t)N * OUT * 2);  // 12.8 MB
  bf16_t* z1 = (bf16_t*)alloc((size_t)N * OUT * 2);  // 12.8 MB
  int2* ed = (int2*)alloc((size_t)E * 8 + 64);       // 12.8 MB (+pad)
  short* Whp = (short*)alloc(16384 * 2);
  short* Wlp = (short*)alloc(16384 * 2);
  int* cnt = (int*)alloc((size_t)N * 4);
  int* rowptr = (int*)alloc((size_t)(N + 1) * 4);
  int* cursor = (int*)alloc((size_t)N * 4);
  float* dinv = (float*)alloc((size_t)N * 4);
  float* selfw = (float*)alloc((size_t)N * 4);
  int NB = (N + 255) / 256;  // 391
  int* bsum = (int*)alloc((size_t)NB * 4);
  (void)ws_size;

  hipLaunchKernelGGL(k_zero, dim3((N + 255) / 256), dim3(256), 0, stream, cnt, N);
  hipLaunchKernelGGL(k_count, dim3((E + 255) / 256), dim3(256), 0, stream, ei + E, cnt, E);
  hipLaunchKernelGGL(k_blocksum, dim3(NB), dim3(256), 0, stream, cnt, bsum, N);
  hipLaunchKernelGGL(k_scanbsum, dim3(1), dim3(512), 0, stream, bsum, NB, rowptr, N, E);
  hipLaunchKernelGGL(k_scan, dim3(NB), dim3(256), 0, stream, cnt, bsum, rowptr, cursor,
                     dinv, selfw, N);
  hipLaunchKernelGGL(k_prep_w, dim3(64), dim3(256), 0, stream, W1, Whp, Wlp);
  hipLaunchKernelGGL(k_gemm_mfma, dim3((N / 16 + 7) / 8), dim3(512), 0, stream, x, Whp,
                     Wlp, b1, h, hb, N);
  hipLaunchKernelGGL(k_scatter, dim3((E + 255) / 256), dim3(256), 0, stream, ei, E, dinv,
                     cursor, ed);

  dim3 pgrid((N + 15) / 16);  // 256 threads = 4 waves x 4 nodes = 16 nodes/block
  const bf16_t* zi = hb;
  bf16_t* zb[2] = {z0, z1};
  for (int it = 0; it < KITER - 1; ++it) {
    bf16_t* zo = zb[it & 1];
    hipLaunchKernelGGL((k_prop<0>), pgrid, dim3(256), 0, stream, rowptr, ed, selfw, zi,
                       hb, h, (void*)zo, N);
    zi = zo;
  }
  hipLaunchKernelGGL((k_prop<1>), pgrid, dim3(256), 0, stream, rowptr, ed, selfw, zi, hb,
                     h, (void*)zfinal, N);
}

// Round 2
// 510.814 us; speedup vs baseline: 1.2702x; 1.2183x over previous
//
#include <hip/hip_runtime.h>

#define KITER 10
#define TILE 4096
typedef unsigned short bf16_t;
typedef __attribute__((ext_vector_type(4))) short bf16x4;
typedef __attribute__((ext_vector_type(8))) short bf16x8;
typedef __attribute__((ext_vector_type(4))) float f32x4;

__device__ __forceinline__ float bf2f(bf16_t u) {
  union { unsigned u; float f; } cv;
  cv.u = ((unsigned)u) << 16;
  return cv.f;
}
__device__ __forceinline__ bf16_t f2bf(float f) {
  unsigned u = __float_as_uint(f);
  unsigned r = (u + 0x7FFFu + ((u >> 16) & 1u)) >> 16;  // round-nearest-even
  return (bf16_t)r;
}

// ---------------- setup kernels ----------------

__global__ void k_zero(int* __restrict__ p, int n) {
  int i = blockIdx.x * blockDim.x + threadIdx.x;
  if (i < n) p[i] = 0;
}

__global__ void k_count(const int* __restrict__ col, int* __restrict__ cnt, int E) {
  int e = blockIdx.x * blockDim.x + threadIdx.x;
  if (e < E) atomicAdd(&cnt[col[e]], 1);
}

__global__ void k_blocksum(const int* __restrict__ cnt, int* __restrict__ bsum, int N) {
  __shared__ int s[256];
  int tid = threadIdx.x;
  int i = blockIdx.x * 256 + tid;
  s[tid] = (i < N) ? cnt[i] : 0;
  __syncthreads();
  for (int off = 128; off > 0; off >>= 1) {
    if (tid < off) s[tid] += s[tid + off];
    __syncthreads();
  }
  if (tid == 0) bsum[blockIdx.x] = s[0];
}

// single block of 512 threads: exclusive scan of bsum (NB <= 512)
__global__ void k_scanbsum(int* __restrict__ bsum, int NB, int* __restrict__ rowptr,
                           int N, int E) {
  __shared__ int s[512];
  int tid = threadIdx.x;
  int v = (tid < NB) ? bsum[tid] : 0;
  s[tid] = v;
  __syncthreads();
  for (int off = 1; off < 512; off <<= 1) {
    int t = (tid >= off) ? s[tid - off] : 0;
    __syncthreads();
    s[tid] += t;
    __syncthreads();
  }
  if (tid < NB) bsum[tid] = s[tid] - v;  // exclusive block offsets
  if (tid == 0) rowptr[N] = E;
}

__global__ void k_scan(const int* __restrict__ cnt, const int* __restrict__ bsum,
                       int* __restrict__ rowptr, float* __restrict__ dinv, int N) {
  __shared__ int s[256];
  int tid = threadIdx.x;
  int i = blockIdx.x * 256 + tid;
  int v = (i < N) ? cnt[i] : 0;
  s[tid] = v;
  __syncthreads();
  for (int off = 1; off < 256; off <<= 1) {
    int t = (tid >= off) ? s[tid - off] : 0;
    __syncthreads();
    s[tid] += t;
    __syncthreads();
  }
  if (i < N) {
    int excl = s[tid] - v + bsum[blockIdx.x];
    rowptr[i] = excl;
    float dg = (float)v + 1.0f;  // deg includes self-loop
    dinv[i] = rsqrtf(dg);
  }
}

// gcursor[b] = start slot of bucket b's region (bucket = 512-node range)
__global__ void k_initcur(const int* __restrict__ rowptr, int* __restrict__ gcursor,
                          int N, int nbuck) {
  int t = threadIdx.x;
  if (t < nbuck) gcursor[t] = rowptr[min(t << 9, N)];
}

// ---------------- bucket sort pass A: tile -> per-bucket coalesced runs ------
// Each block: 4096 edges. LDS histogram over 196 buckets (target>>9), LDS
// reorder grouped by bucket, one global atomic per bucket to reserve segment,
// then contiguous run writes (write amp ~1.3 vs ~8x for random 8B scatter).
__global__ __launch_bounds__(256) void k_bucket(const int* __restrict__ ei, int E,
                                                int* __restrict__ gcursor,
                                                int2* __restrict__ barr) {
  __shared__ int hist[256];
  __shared__ int scn[256];
  __shared__ int excl[256];
  __shared__ int gb[256];
  __shared__ unsigned char lb[TILE];
  __shared__ int2 stg[TILE];
  int t = threadIdx.x;
  int base = blockIdx.x * TILE;
  hist[t] = 0;
  __syncthreads();
  int s[16], c[16];
#pragma unroll
  for (int i = 0; i < 16; ++i) {
    int e = base + i * 256 + t;
    if (e < E) {
      s[i] = ei[e];
      c[i] = ei[E + e];
      atomicAdd(&hist[c[i] >> 9], 1);
    } else {
      c[i] = -1;
    }
  }
  __syncthreads();
  int h = hist[t];
  scn[t] = h;
  __syncthreads();
  for (int off = 1; off < 256; off <<= 1) {
    int v = (t >= off) ? scn[t - off] : 0;
    __syncthreads();
    scn[t] += v;
    __syncthreads();
  }
  excl[t] = scn[t] - h;
  gb[t] = (h > 0) ? atomicAdd(&gcursor[t], h) : 0;
  __syncthreads();
  hist[t] = excl[t];  // reuse as local placement cursor
  __syncthreads();
#pragma unroll
  for (int i = 0; i < 16; ++i) {
    if (c[i] >= 0) {
      int b = c[i] >> 9;
      int p = atomicAdd(&hist[b], 1);
      stg[p] = make_int2(s[i], c[i]);
      lb[p] = (unsigned char)b;
    }
  }
  __syncthreads();
  int cntE = min(TILE, E - base);
#pragma unroll
  for (int i = 0; i < 16; ++i) {
    int p = i * 256 + t;
    if (p < cntE) {
      int b = lb[p];
      barr[gb[b] + (p - excl[b])] = stg[p];
    }
  }
}

// ---------------- bucket sort pass B: bucket -> exact CSR slots --------------
// One block per bucket (512-node range). LDS per-node cursors; destination
// region (~32 KB) written entirely by this block -> full-line writebacks.
// With pre-scaled z, payload is just the source index (4 B).
__global__ __launch_bounds__(256) void k_finalize(const int* __restrict__ rowptr,
                                                  const int2* __restrict__ barr,
                                                  int* __restrict__ ed4, int N) {
  __shared__ int cur[512];
  int b = blockIdx.x;
  int node0 = b << 9;
  int node1 = min(node0 + 512, N);
  int t = threadIdx.x;
  for (int i = t; i < node1 - node0; i += 256) cur[i] = rowptr[node0 + i];
  int R0 = rowptr[node0];
  int R1 = rowptr[node1];
  __syncthreads();
  for (int idx = R0 + t; idx < R1; idx += 256) {
    int2 v = barr[idx];
    int slot = atomicAdd(&cur[v.y - node0], 1);
    ed4[slot] = v.x;
  }
}

// ---------------- W pack: split fp32 W into bf16 hi/lo, MFMA B-frag layout ----
__global__ void k_prep_w(const float* __restrict__ W, short* __restrict__ Whp,
                         short* __restrict__ Wlp) {
  int i = blockIdx.x * 256 + threadIdx.x;  // 0..16383
  int j = i & 7;
  int lane = (i >> 3) & 63;
  int cg = (i >> 9) & 3;
  int kc = i >> 11;
  int k = kc * 32 + (lane >> 4) * 8 + j;
  int col = cg * 16 + (lane & 15);
  float w = W[k * 64 + col];
  unsigned u = __float_as_uint(w);
  unsigned hbits = u & 0xFFFF0000u;  // truncate: residual captured exactly by lo
  Whp[i] = (short)(hbits >> 16);
  Wlp[i] = (short)f2bf(w - __uint_as_float(hbits));
}

// ---------------- h = relu(x @ W1 + b1) via split-precision bf16 MFMA --------
// Also emits zs0 = bf16(dinv * h): pre-scaled propagation state.
__global__ __launch_bounds__(512) void k_gemm_mfma(const float* __restrict__ x,
                                                   const short* __restrict__ Whp,
                                                   const short* __restrict__ Wlp,
                                                   const float* __restrict__ b,
                                                   const float* __restrict__ dinv,
                                                   float* __restrict__ h,
                                                   bf16_t* __restrict__ hb,
                                                   bf16_t* __restrict__ zs0, int N) {
  __shared__ short WhS[16384];  // 32 KB
  __shared__ short WlS[16384];  // 32 KB
  int tid = threadIdx.x;
  for (int i = tid; i < 2048; i += 512) {
    ((int4*)WhS)[i] = ((const int4*)Whp)[i];
    ((int4*)WlS)[i] = ((const int4*)Wlp)[i];
  }
  __syncthreads();
  int wid = tid >> 6;
  int lane = tid & 63;
  int row0 = (blockIdx.x * 8 + wid) * 16;
  if (row0 >= N) return;
  int arow = row0 + (lane & 15);
  if (arow >= N) arow = N - 1;  // clamp (stores guarded)
  const float* xr = x + (size_t)arow * 256 + (lane >> 4) * 8;

  f32x4 xa[8], xb[8];
#pragma unroll
  for (int kc = 0; kc < 8; ++kc) {
    xa[kc] = *(const f32x4*)(xr + kc * 32);
    xb[kc] = *(const f32x4*)(xr + kc * 32 + 4);
  }

  f32x4 acc[4];
#pragma unroll
  for (int cg = 0; cg < 4; ++cg) acc[cg] = (f32x4){0.f, 0.f, 0.f, 0.f};

#pragma unroll
  for (int kc = 0; kc < 8; ++kc) {
    float f[8] = {xa[kc].x, xa[kc].y, xa[kc].z, xa[kc].w,
                  xb[kc].x, xb[kc].y, xb[kc].z, xb[kc].w};
    bf16x8 xh, xl;
#pragma unroll
    for (int j = 0; j < 8; ++j) {
      unsigned u = __float_as_uint(f[j]);
      unsigned hbits = u & 0xFFFF0000u;
      xh[j] = (short)(hbits >> 16);
      xl[j] = (short)f2bf(f[j] - __uint_as_float(hbits));
    }
#pragma unroll
    for (int cg = 0; cg < 4; ++cg) {
      const bf16x8 wh = *(const bf16x8*)&WhS[((kc * 4 + cg) * 64 + lane) * 8];
      const bf16x8 wl = *(const bf16x8*)&WlS[((kc * 4 + cg) * 64 + lane) * 8];
      acc[cg] = __builtin_amdgcn_mfma_f32_16x16x32_bf16(xh, wh, acc[cg], 0, 0, 0);
      acc[cg] = __builtin_amdgcn_mfma_f32_16x16x32_bf16(xl, wh, acc[cg], 0, 0, 0);
      acc[cg] = __builtin_amdgcn_mfma_f32_16x16x32_bf16(xh, wl, acc[cg], 0, 0, 0);
    }
  }

  int rbase = row0 + (lane >> 4) * 4;
  float dv[4];
#pragma unroll
  for (int r = 0; r < 4; ++r) {
    int row = rbase + r;
    dv[r] = (row < N) ? dinv[row] : 0.f;
  }
#pragma unroll
  for (int cg = 0; cg < 4; ++cg) {
    int col = cg * 16 + (lane & 15);
    float bias = b[col];
#pragma unroll
    for (int r = 0; r < 4; ++r) {
      int row = rbase + r;
      if (row < N) {
        float v = fmaxf(acc[cg][r] + bias, 0.f);
        size_t o = (size_t)row * 64 + col;
        h[o] = v;
        hb[o] = f2bf(v);
        zs0[o] = f2bf(dv[r] * v);
      }
    }
  }
}

// ---------------- propagation v3: pre-scaled z, 4-byte edges -----------------
// zs = dinv*z. Per edge: one 4B index load + one 8B bf16x4 gather + 4 adds.
// z_new = 0.9*dinv_c*(sum zs[src] + zs[c]) + 0.1*h; store zs_new = dinv_c*z_new.
template <int LAST>
__global__ __launch_bounds__(256) void k_prop(const int* __restrict__ rowptr,
                                              const int* __restrict__ ed4,
                                              const float* __restrict__ dinv,
                                              const bf16_t* __restrict__ zin,
                                              const bf16_t* __restrict__ hbi,
                                              const float* __restrict__ hf,
                                              void* __restrict__ zout_, int N) {
  int tid = threadIdx.x;
  int lane = tid & 63;
  int u = lane & 15;  // channel quartet: channels u*4 .. u*4+3
  int g = lane >> 4;  // node sub-index within wave (0..3)
  int node = blockIdx.x * 16 + (tid >> 6) * 4 + g;
  bool live = node < N;
  if (!live) node = N - 1;  // clamp; stores guarded
  int beg = rowptr[node];
  int end = rowptr[node + 1];
  float dvc = dinv[node];
  size_t base = (size_t)node * 64 + u * 4;

  union U { bf16x4 v; unsigned d[2]; };
  U zs;
  zs.v = *(const bf16x4*)(zin + base);  // self term (already dinv-scaled)
  float acc0 = __uint_as_float(zs.d[0] << 16);
  float acc1 = __uint_as_float(zs.d[0] & 0xFFFF0000u);
  float acc2 = __uint_as_float(zs.d[1] << 16);
  float acc3 = __uint_as_float(zs.d[1] & 0xFFFF0000u);

  int e = beg;
  for (; e + 3 < end; e += 4) {
    int q0 = ed4[e], q1 = ed4[e + 1], q2 = ed4[e + 2], q3 = ed4[e + 3];
    U z0, z1, z2, z3;
    z0.v = *(const bf16x4*)(zin + (size_t)q0 * 64 + u * 4);
    z1.v = *(const bf16x4*)(zin + (size_t)q1 * 64 + u * 4);
    z2.v = *(const bf16x4*)(zin + (size_t)q2 * 64 + u * 4);
    z3.v = *(const bf16x4*)(zin + (size_t)q3 * 64 + u * 4);
    acc0 += __uint_as_float(z0.d[0] << 16) + __uint_as_float(z1.d[0] << 16) +
            __uint_as_float(z2.d[0] << 16) + __uint_as_float(z3.d[0] << 16);
    acc1 += __uint_as_float(z0.d[0] & 0xFFFF0000u) + __uint_as_float(z1.d[0] & 0xFFFF0000u) +
            __uint_as_float(z2.d[0] & 0xFFFF0000u) + __uint_as_float(z3.d[0] & 0xFFFF0000u);
    acc2 += __uint_as_float(z0.d[1] << 16) + __uint_as_float(z1.d[1] << 16) +
            __uint_as_float(z2.d[1] << 16) + __uint_as_float(z3.d[1] << 16);
    acc3 += __uint_as_float(z0.d[1] & 0xFFFF0000u) + __uint_as_float(z1.d[1] & 0xFFFF0000u) +
            __uint_as_float(z2.d[1] & 0xFFFF0000u) + __uint_as_float(z3.d[1] & 0xFFFF0000u);
  }
  for (; e < end; ++e) {
    int q = ed4[e];
    U z0;
    z0.v = *(const bf16x4*)(zin + (size_t)q * 64 + u * 4);
    acc0 += __uint_as_float(z0.d[0] << 16);
    acc1 += __uint_as_float(z0.d[0] & 0xFFFF0000u);
    acc2 += __uint_as_float(z0.d[1] << 16);
    acc3 += __uint_as_float(z0.d[1] & 0xFFFF0000u);
  }

  float sca = 0.9f * dvc;
  if (LAST) {
    f32x4 hv = *(const f32x4*)(hf + base);
    f32x4 res;
    res.x = sca * acc0 + 0.1f * hv.x;
    res.y = sca * acc1 + 0.1f * hv.y;
    res.z = sca * acc2 + 0.1f * hv.z;
    res.w = sca * acc3 + 0.1f * hv.w;
    if (live) *(f32x4*)((float*)zout_ + base) = res;
  } else {
    U hv;
    hv.v = *(const bf16x4*)(hbi + base);
    float r0 = dvc * (sca * acc0 + 0.1f * __uint_as_float(hv.d[0] << 16));
    float r1 = dvc * (sca * acc1 + 0.1f * __uint_as_float(hv.d[0] & 0xFFFF0000u));
    float r2 = dvc * (sca * acc2 + 0.1f * __uint_as_float(hv.d[1] << 16));
    float r3 = dvc * (sca * acc3 + 0.1f * __uint_as_float(hv.d[1] & 0xFFFF0000u));
    unsigned o0 = (unsigned)f2bf(r0) | (((unsigned)f2bf(r1)) << 16);
    unsigned o1 = (unsigned)f2bf(r2) | (((unsigned)f2bf(r3)) << 16);
    if (live) {
      uint2 o = make_uint2(o0, o1);
      *(uint2*)((bf16_t*)zout_ + base) = o;
    }
  }
}

// ---------------- launch ----------------

extern "C" void kernel_launch(void* const* d_in, const int* in_sizes, int n_in,
                              void* d_out, int out_size, void* d_ws, size_t ws_size,
                              hipStream_t stream) {
  const float* x = (const float*)d_in[0];
  const int* ei = (const int*)d_in[1];  // int32 per harness contract
  const float* W1 = (const float*)d_in[2];
  const float* b1 = (const float*)d_in[3];
  float* zfinal = (float*)d_out;

  int OUT = in_sizes[3];        // 64
  int IN = in_sizes[2] / OUT;   // 256
  int N = in_sizes[0] / IN;     // 100000
  int E = in_sizes[1] / 2;      // 1600000

  char* ws = (char*)d_ws;
  size_t off = 0;
  auto alloc = [&](size_t bytes) -> char* {
    char* p = ws + off;
    off = (off + bytes + 255) & ~(size_t)255;
    return p;
  };
  float* h = (float*)alloc((size_t)N * OUT * 4);      // 25.6 MB
  bf16_t* hb = (bf16_t*)alloc((size_t)N * OUT * 2);   // 12.8 MB
  bf16_t* zs0 = (bf16_t*)alloc((size_t)N * OUT * 2);  // 12.8 MB
  bf16_t* z0 = (bf16_t*)alloc((size_t)N * OUT * 2);   // 12.8 MB
  bf16_t* z1 = (bf16_t*)alloc((size_t)N * OUT * 2);   // 12.8 MB
  int2* barr = (int2*)alloc((size_t)E * 8 + 64);      // 12.8 MB
  int* ed4 = (int*)alloc((size_t)E * 4 + 64);         // 6.4 MB
  short* Whp = (short*)alloc(16384 * 2);
  short* Wlp = (short*)alloc(16384 * 2);
  int* cnt = (int*)alloc((size_t)N * 4);
  int* rowptr = (int*)alloc((size_t)(N + 1) * 4);
  float* dinv = (float*)alloc((size_t)N * 4);
  int* gcursor = (int*)alloc(256 * 4);
  int NB = (N + 255) / 256;  // 391
  int* bsum = (int*)alloc((size_t)NB * 4);
  (void)ws_size;

  int nbuck = (N + 511) >> 9;  // 196

  hipLaunchKernelGGL(k_zero, dim3((N + 255) / 256), dim3(256), 0, stream, cnt, N);
  hipLaunchKernelGGL(k_count, dim3((E + 255) / 256), dim3(256), 0, stream, ei + E, cnt, E);
  hipLaunchKernelGGL(k_blocksum, dim3(NB), dim3(256), 0, stream, cnt, bsum, N);
  hipLaunchKernelGGL(k_scanbsum, dim3(1), dim3(512), 0, stream, bsum, NB, rowptr, N, E);
  hipLaunchKernelGGL(k_scan, dim3(NB), dim3(256), 0, stream, cnt, bsum, rowptr, dinv, N);
  hipLaunchKernelGGL(k_initcur, dim3(1), dim3(256), 0, stream, rowptr, gcursor, N, nbuck);
  hipLaunchKernelGGL(k_prep_w, dim3(64), dim3(256), 0, stream, W1, Whp, Wlp);
  hipLaunchKernelGGL(k_gemm_mfma, dim3((N / 16 + 7) / 8), dim3(512), 0, stream, x, Whp,
                     Wlp, b1, dinv, h, hb, zs0, N);
  hipLaunchKernelGGL(k_bucket, dim3((E + TILE - 1) / TILE), dim3(256), 0, stream, ei, E,
                     gcursor, barr);
  hipLaunchKernelGGL(k_finalize, dim3(nbuck), dim3(256), 0, stream, rowptr, barr, ed4, N);

  dim3 pgrid((N + 15) / 16);  // 256 threads = 4 waves x 4 nodes = 16 nodes/block
  const bf16_t* zi = zs0;
  bf16_t* zb[2] = {z0, z1};
  for (int it = 0; it < KITER - 1; ++it) {
    bf16_t* zo = zb[it & 1];
    hipLaunchKernelGGL((k_prop<0>), pgrid, dim3(256), 0, stream, rowptr, ed4, dinv, zi,
                       hb, h, (void*)zo, N);
    zi = zo;
  }
  hipLaunchKernelGGL((k_prop<1>), pgrid, dim3(256), 0, stream, rowptr, ed4, dinv, zi, hb,
                     h, (void*)zfinal, N);
}

// Round 3
// 442.936 us; speedup vs baseline: 1.4648x; 1.1532x over previous
//
#include <hip/hip_runtime.h>

#define KITER 10
#define TILE 4096
#define BCAP 16384  // bucket staging capacity (expected 8192/bucket, +90 sigma)
typedef unsigned short bf16_t;
typedef __attribute__((ext_vector_type(4))) short bf16x4;
typedef __attribute__((ext_vector_type(8))) short bf16x8;
typedef __attribute__((ext_vector_type(4))) float f32x4;

__device__ __forceinline__ float bf2f(bf16_t u) {
  union { unsigned u; float f; } cv;
  cv.u = ((unsigned)u) << 16;
  return cv.f;
}
__device__ __forceinline__ bf16_t f2bf(float f) {
  unsigned u = __float_as_uint(f);
  unsigned r = (u + 0x7FFFu + ((u >> 16) & 1u)) >> 16;  // round-nearest-even
  return (bf16_t)r;
}

// ---------------- bucket cursor init: bcur[b] = b*BCAP ----------------
__global__ void k_initb(int* __restrict__ bcur, int nbuck) {
  int i = threadIdx.x;
  if (i < nbuck) bcur[i] = i * BCAP;
}

// ---------------- bucket sort pass A: tile -> per-bucket coalesced runs ------
// Each block: 4096 edges. LDS histogram over buckets (target>>9), LDS reorder
// grouped by bucket, one global atomic per bucket to reserve a segment slice,
// contiguous run writes. No dependency on counts/rowptr (fixed-capacity segs).
__global__ __launch_bounds__(256) void k_bucket(const int* __restrict__ ei, int E,
                                                int* __restrict__ bcur,
                                                int2* __restrict__ barr) {
  __shared__ int hist[256];
  __shared__ int scn[256];
  __shared__ int excl[256];
  __shared__ int gb[256];
  __shared__ unsigned char lb[TILE];
  __shared__ int2 stg[TILE];
  int t = threadIdx.x;
  int base = blockIdx.x * TILE;
  hist[t] = 0;
  __syncthreads();
  int s[16], c[16];
#pragma unroll
  for (int i = 0; i < 16; ++i) {
    int e = base + i * 256 + t;
    if (e < E) {
      s[i] = ei[e];
      c[i] = ei[E + e];
      atomicAdd(&hist[c[i] >> 9], 1);
    } else {
      c[i] = -1;
    }
  }
  __syncthreads();
  int h = hist[t];
  scn[t] = h;
  __syncthreads();
  for (int off = 1; off < 256; off <<= 1) {
    int v = (t >= off) ? scn[t - off] : 0;
    __syncthreads();
    scn[t] += v;
    __syncthreads();
  }
  excl[t] = scn[t] - h;
  gb[t] = (h > 0) ? atomicAdd(&bcur[t], h) : 0;
  __syncthreads();
  hist[t] = excl[t];  // reuse as local placement cursor
  __syncthreads();
#pragma unroll
  for (int i = 0; i < 16; ++i) {
    if (c[i] >= 0) {
      int b = c[i] >> 9;
      int p = atomicAdd(&hist[b], 1);
      stg[p] = make_int2(s[i], c[i]);
      lb[p] = (unsigned char)b;
    }
  }
  __syncthreads();
  int cntE = min(TILE, E - base);
#pragma unroll
  for (int i = 0; i < 16; ++i) {
    int p = i * 256 + t;
    if (p < cntE) {
      int b = lb[p];
      barr[gb[b] + (p - excl[b])] = stg[p];
    }
  }
}

// ---------------- bucket-level exclusive prefix (nbuck <= 256), 1 block ------
__global__ void k_bscan(const int* __restrict__ bcur, int* __restrict__ bstart,
                        int nbuck, int* __restrict__ rowptr, int N, int E) {
  __shared__ int s[256];
  int t = threadIdx.x;
  int v = (t < nbuck) ? (bcur[t] - t * BCAP) : 0;
  s[t] = v;
  __syncthreads();
  for (int off = 1; off < 256; off <<= 1) {
    int tv = (t >= off) ? s[t - off] : 0;
    __syncthreads();
    s[t] += tv;
    __syncthreads();
  }
  if (t < nbuck) bstart[t] = s[t] - v;
  if (t == 0) rowptr[N] = E;
}

// ---------------- pass B: bucket -> CSR; also emits rowptr & dinv ------------
// One 512-thread block per bucket (512-node range). Counts per-node degrees in
// LDS from the staging segment, scans, writes rowptr/dinv (coalesced), then
// places edges at exact CSR slots. Destination region written by one block ->
// full-line writebacks. Payload is the bare source index (pre-scaled z).
__global__ __launch_bounds__(512) void k_finalize(const int* __restrict__ bcur,
                                                  const int* __restrict__ bstart,
                                                  const int2* __restrict__ barr,
                                                  int* __restrict__ rowptr,
                                                  float* __restrict__ dinv,
                                                  int* __restrict__ ed4, int N) {
  __shared__ int cnt[512];
  __shared__ int sbuf[512];
  __shared__ int cur[512];
  int b = blockIdx.x;
  int node0 = b << 9;
  int nn = min(512, N - node0);
  int t = threadIdx.x;
  cnt[t] = 0;
  __syncthreads();
  int m = bcur[b] - b * BCAP;  // edges in this bucket
  int src = b * BCAP;
  int bst = bstart[b];
  for (int i = t; i < m; i += 512) atomicAdd(&cnt[barr[src + i].y - node0], 1);
  __syncthreads();
  int v = cnt[t];
  sbuf[t] = v;
  __syncthreads();
  for (int off = 1; off < 512; off <<= 1) {
    int tv = (t >= off) ? sbuf[t - off] : 0;
    __syncthreads();
    sbuf[t] += tv;
    __syncthreads();
  }
  int excl = sbuf[t] - v;
  if (t < nn) {
    rowptr[node0 + t] = bst + excl;
    dinv[node0 + t] = rsqrtf((float)v + 1.0f);
  }
  cur[t] = bst + excl;
  __syncthreads();
  for (int i = t; i < m; i += 512) {
    int2 q = barr[src + i];
    int slot = atomicAdd(&cur[q.y - node0], 1);
    ed4[slot] = q.x;
  }
}

// ---------------- W pack: split fp32 W into bf16 hi/lo, MFMA B-frag layout ----
__global__ void k_prep_w(const float* __restrict__ W, short* __restrict__ Whp,
                         short* __restrict__ Wlp) {
  int i = blockIdx.x * 256 + threadIdx.x;  // 0..16383
  int j = i & 7;
  int lane = (i >> 3) & 63;
  int cg = (i >> 9) & 3;
  int kc = i >> 11;
  int k = kc * 32 + (lane >> 4) * 8 + j;
  int col = cg * 16 + (lane & 15);
  float w = W[k * 64 + col];
  unsigned u = __float_as_uint(w);
  unsigned hbits = u & 0xFFFF0000u;  // truncate: residual captured exactly by lo
  Whp[i] = (short)(hbits >> 16);
  Wlp[i] = (short)f2bf(w - __uint_as_float(hbits));
}

// ---------------- h = relu(x @ W1 + b1), split-precision bf16 MFMA -----------
// No LDS: W fragments read per-wave from global (64 KB table, L2/L3-hot).
// 256 threads = 4 waves, one 16-row tile per wave; x loaded in two 4-kc halves
// to bound VGPR. Emits h (fp32), hb (bf16), zs0 = bf16(dinv*h).
__global__ __launch_bounds__(256) void k_gemm_mfma(const float* __restrict__ x,
                                                   const short* __restrict__ Whp,
                                                   const short* __restrict__ Wlp,
                                                   const float* __restrict__ b,
                                                   const float* __restrict__ dinv,
                                                   float* __restrict__ h,
                                                   bf16_t* __restrict__ hb,
                                                   bf16_t* __restrict__ zs0, int N) {
  int tid = threadIdx.x;
  int wid = tid >> 6;
  int lane = tid & 63;
  int row0 = (blockIdx.x * 4 + wid) * 16;
  if (row0 >= N) return;
  int arow = row0 + (lane & 15);
  if (arow >= N) arow = N - 1;  // clamp (stores guarded)
  const float* xr = x + (size_t)arow * 256 + (lane >> 4) * 8;

  f32x4 acc[4];
#pragma unroll
  for (int cg = 0; cg < 4; ++cg) acc[cg] = (f32x4){0.f, 0.f, 0.f, 0.f};

#pragma unroll
  for (int half = 0; half < 2; ++half) {
    f32x4 xa[4], xb[4];
#pragma unroll
    for (int k2 = 0; k2 < 4; ++k2) {
      xa[k2] = *(const f32x4*)(xr + (half * 4 + k2) * 32);
      xb[k2] = *(const f32x4*)(xr + (half * 4 + k2) * 32 + 4);
    }
#pragma unroll
    for (int k2 = 0; k2 < 4; ++k2) {
      int kc = half * 4 + k2;
      float f[8] = {xa[k2].x, xa[k2].y, xa[k2].z, xa[k2].w,
                    xb[k2].x, xb[k2].y, xb[k2].z, xb[k2].w};
      bf16x8 xh, xl;
#pragma unroll
      for (int j = 0; j < 8; ++j) {
        unsigned u = __float_as_uint(f[j]);
        unsigned hbits = u & 0xFFFF0000u;
        xh[j] = (short)(hbits >> 16);
        xl[j] = (short)f2bf(f[j] - __uint_as_float(hbits));
      }
#pragma unroll
      for (int cg = 0; cg < 4; ++cg) {
        const bf16x8 wh = *(const bf16x8*)&Whp[((kc * 4 + cg) * 64 + lane) * 8];
        const bf16x8 wl = *(const bf16x8*)&Wlp[((kc * 4 + cg) * 64 + lane) * 8];
        acc[cg] = __builtin_amdgcn_mfma_f32_16x16x32_bf16(xh, wh, acc[cg], 0, 0, 0);
        acc[cg] = __builtin_amdgcn_mfma_f32_16x16x32_bf16(xl, wh, acc[cg], 0, 0, 0);
        acc[cg] = __builtin_amdgcn_mfma_f32_16x16x32_bf16(xh, wl, acc[cg], 0, 0, 0);
      }
    }
  }

  int rbase = row0 + (lane >> 4) * 4;
  float dv[4];
#pragma unroll
  for (int r = 0; r < 4; ++r) {
    int row = rbase + r;
    dv[r] = (row < N) ? dinv[row] : 0.f;
  }
#pragma unroll
  for (int cg = 0; cg < 4; ++cg) {
    int col = cg * 16 + (lane & 15);
    float bias = b[col];
#pragma unroll
    for (int r = 0; r < 4; ++r) {
      int row = rbase + r;
      if (row < N) {
        float v = fmaxf(acc[cg][r] + bias, 0.f);
        size_t o = (size_t)row * 64 + col;
        h[o] = v;
        hb[o] = f2bf(v);
        zs0[o] = f2bf(dv[r] * v);
      }
    }
  }
}

// ---------------- propagation: pre-scaled z, 4-byte edges --------------------
// zs = dinv*z. Per edge: one 4B index load + one 8B bf16x4 gather + 4 adds.
// z_new = 0.9*dinv_c*(sum zs[src] + zs[c]) + 0.1*h; store zs_new = dinv_c*z_new.
template <int LAST>
__global__ __launch_bounds__(256) void k_prop(const int* __restrict__ rowptr,
                                              const int* __restrict__ ed4,
                                              const float* __restrict__ dinv,
                                              const bf16_t* __restrict__ zin,
                                              const bf16_t* __restrict__ hbi,
                                              const float* __restrict__ hf,
                                              void* __restrict__ zout_, int N) {
  int tid = threadIdx.x;
  int lane = tid & 63;
  int u = lane & 15;  // channel quartet: channels u*4 .. u*4+3
  int g = lane >> 4;  // node sub-index within wave (0..3)
  int node = blockIdx.x * 16 + (tid >> 6) * 4 + g;
  bool live = node < N;
  if (!live) node = N - 1;  // clamp; stores guarded
  int beg = rowptr[node];
  int end = rowptr[node + 1];
  float dvc = dinv[node];
  size_t base = (size_t)node * 64 + u * 4;

  union U { bf16x4 v; unsigned d[2]; };
  U zs;
  zs.v = *(const bf16x4*)(zin + base);  // self term (already dinv-scaled)
  float acc0 = __uint_as_float(zs.d[0] << 16);
  float acc1 = __uint_as_float(zs.d[0] & 0xFFFF0000u);
  float acc2 = __uint_as_float(zs.d[1] << 16);
  float acc3 = __uint_as_float(zs.d[1] & 0xFFFF0000u);

  int e = beg;
  for (; e + 3 < end; e += 4) {
    int q0 = ed4[e], q1 = ed4[e + 1], q2 = ed4[e + 2], q3 = ed4[e + 3];
    U z0, z1, z2, z3;
    z0.v = *(const bf16x4*)(zin + (size_t)q0 * 64 + u * 4);
    z1.v = *(const bf16x4*)(zin + (size_t)q1 * 64 + u * 4);
    z2.v = *(const bf16x4*)(zin + (size_t)q2 * 64 + u * 4);
    z3.v = *(const bf16x4*)(zin + (size_t)q3 * 64 + u * 4);
    acc0 += __uint_as_float(z0.d[0] << 16) + __uint_as_float(z1.d[0] << 16) +
            __uint_as_float(z2.d[0] << 16) + __uint_as_float(z3.d[0] << 16);
    acc1 += __uint_as_float(z0.d[0] & 0xFFFF0000u) + __uint_as_float(z1.d[0] & 0xFFFF0000u) +
            __uint_as_float(z2.d[0] & 0xFFFF0000u) + __uint_as_float(z3.d[0] & 0xFFFF0000u);
    acc2 += __uint_as_float(z0.d[1] << 16) + __uint_as_float(z1.d[1] << 16) +
            __uint_as_float(z2.d[1] << 16) + __uint_as_float(z3.d[1] << 16);
    acc3 += __uint_as_float(z0.d[1] & 0xFFFF0000u) + __uint_as_float(z1.d[1] & 0xFFFF0000u) +
            __uint_as_float(z2.d[1] & 0xFFFF0000u) + __uint_as_float(z3.d[1] & 0xFFFF0000u);
  }
  for (; e < end; ++e) {
    int q = ed4[e];
    U z0;
    z0.v = *(const bf16x4*)(zin + (size_t)q * 64 + u * 4);
    acc0 += __uint_as_float(z0.d[0] << 16);
    acc1 += __uint_as_float(z0.d[0] & 0xFFFF0000u);
    acc2 += __uint_as_float(z0.d[1] << 16);
    acc3 += __uint_as_float(z0.d[1] & 0xFFFF0000u);
  }

  float sca = 0.9f * dvc;
  if (LAST) {
    f32x4 hv = *(const f32x4*)(hf + base);
    f32x4 res;
    res.x = sca * acc0 + 0.1f * hv.x;
    res.y = sca * acc1 + 0.1f * hv.y;
    res.z = sca * acc2 + 0.1f * hv.z;
    res.w = sca * acc3 + 0.1f * hv.w;
    if (live) *(f32x4*)((float*)zout_ + base) = res;
  } else {
    U hv;
    hv.v = *(const bf16x4*)(hbi + base);
    float r0 = dvc * (sca * acc0 + 0.1f * __uint_as_float(hv.d[0] << 16));
    float r1 = dvc * (sca * acc1 + 0.1f * __uint_as_float(hv.d[0] & 0xFFFF0000u));
    float r2 = dvc * (sca * acc2 + 0.1f * __uint_as_float(hv.d[1] << 16));
    float r3 = dvc * (sca * acc3 + 0.1f * __uint_as_float(hv.d[1] & 0xFFFF0000u));
    unsigned o0 = (unsigned)f2bf(r0) | (((unsigned)f2bf(r1)) << 16);
    unsigned o1 = (unsigned)f2bf(r2) | (((unsigned)f2bf(r3)) << 16);
    if (live) {
      uint2 o = make_uint2(o0, o1);
      *(uint2*)((bf16_t*)zout_ + base) = o;
    }
  }
}

// ---------------- launch ----------------

extern "C" void kernel_launch(void* const* d_in, const int* in_sizes, int n_in,
                              void* d_out, int out_size, void* d_ws, size_t ws_size,
                              hipStream_t stream) {
  const float* x = (const float*)d_in[0];
  const int* ei = (const int*)d_in[1];  // int32 per harness contract
  const float* W1 = (const float*)d_in[2];
  const float* b1 = (const float*)d_in[3];
  float* zfinal = (float*)d_out;

  int OUT = in_sizes[3];        // 64
  int IN = in_sizes[2] / OUT;   // 256
  int N = in_sizes[0] / IN;     // 100000
  int E = in_sizes[1] / 2;      // 1600000

  char* ws = (char*)d_ws;
  size_t off = 0;
  auto alloc = [&](size_t bytes) -> char* {
    char* p = ws + off;
    off = (off + bytes + 255) & ~(size_t)255;
    return p;
  };
  int nbuck = (N + 511) >> 9;  // 196
  float* h = (float*)alloc((size_t)N * OUT * 4);       // 25.6 MB
  bf16_t* hb = (bf16_t*)alloc((size_t)N * OUT * 2);    // 12.8 MB
  bf16_t* zs0 = (bf16_t*)alloc((size_t)N * OUT * 2);   // 12.8 MB
  bf16_t* z0 = (bf16_t*)alloc((size_t)N * OUT * 2);    // 12.8 MB
  bf16_t* z1 = (bf16_t*)alloc((size_t)N * OUT * 2);    // 12.8 MB
  int2* barr = (int2*)alloc((size_t)nbuck * BCAP * 8); // 25.7 MB
  int* ed4 = (int*)alloc((size_t)E * 4 + 64);          // 6.4 MB
  short* Whp = (short*)alloc(16384 * 2);
  short* Wlp = (short*)alloc(16384 * 2);
  int* rowptr = (int*)alloc((size_t)(N + 1) * 4);
  float* dinv = (float*)alloc((size_t)N * 4);
  int* bcur = (int*)alloc(256 * 4);
  int* bstart = (int*)alloc(256 * 4);
  (void)ws_size;

  hipLaunchKernelGGL(k_initb, dim3(1), dim3(256), 0, stream, bcur, nbuck);
  hipLaunchKernelGGL(k_bucket, dim3((E + TILE - 1) / TILE), dim3(256), 0, stream, ei, E,
                     bcur, barr);
  hipLaunchKernelGGL(k_bscan, dim3(1), dim3(256), 0, stream, bcur, bstart, nbuck, rowptr,
                     N, E);
  hipLaunchKernelGGL(k_finalize, dim3(nbuck), dim3(512), 0, stream, bcur, bstart, barr,
                     rowptr, dinv, ed4, N);
  hipLaunchKernelGGL(k_prep_w, dim3(64), dim3(256), 0, stream, W1, Whp, Wlp);
  hipLaunchKernelGGL(k_gemm_mfma, dim3(((N + 15) / 16 + 3) / 4), dim3(256), 0, stream, x,
                     Whp, Wlp, b1, dinv, h, hb, zs0, N);

  dim3 pgrid((N + 15) / 16);  // 256 threads = 4 waves x 4 nodes = 16 nodes/block
  const bf16_t* zi = zs0;
  bf16_t* zb[2] = {z0, z1};
  for (int it = 0; it < KITER - 1; ++it) {
    bf16_t* zo = zb[it & 1];
    hipLaunchKernelGGL((k_prop<0>), pgrid, dim3(256), 0, stream, rowptr, ed4, dinv, zi,
                       hb, h, (void*)zo, N);
    zi = zo;
  }
  hipLaunchKernelGGL((k_prop<1>), pgrid, dim3(256), 0, stream, rowptr, ed4, dinv, zi, hb,
                     h, (void*)zfinal, N);
}

// Round 4
// 423.873 us; speedup vs baseline: 1.5307x; 1.0450x over previous
//
#include <hip/hip_runtime.h>

#define KITER 10
#define TILE 4096
#define BCAP 16384  // bucket staging capacity (expected 8192/bucket, +90 sigma)
typedef unsigned short bf16_t;
typedef __attribute__((ext_vector_type(4))) short bf16x4;
typedef __attribute__((ext_vector_type(8))) short bf16x8;
typedef __attribute__((ext_vector_type(4))) float f32x4;

__device__ __forceinline__ float bf2f(bf16_t u) {
  union { unsigned u; float f; } cv;
  cv.u = ((unsigned)u) << 16;
  return cv.f;
}
__device__ __forceinline__ bf16_t f2bf(float f) {
  unsigned u = __float_as_uint(f);
  unsigned r = (u + 0x7FFFu + ((u >> 16) & 1u)) >> 16;  // round-nearest-even
  return (bf16_t)r;
}

// ---------------- bucket cursor init: bcur[b] = b*BCAP ----------------
__global__ void k_initb(int* __restrict__ bcur, int nbuck) {
  int i = threadIdx.x;
  if (i < nbuck) bcur[i] = i * BCAP;
}

// ---------------- bucket sort pass A: tile -> per-bucket coalesced runs ------
__global__ __launch_bounds__(256) void k_bucket(const int* __restrict__ ei, int E,
                                                int* __restrict__ bcur,
                                                int2* __restrict__ barr) {
  __shared__ int hist[256];
  __shared__ int scn[256];
  __shared__ int excl[256];
  __shared__ int gb[256];
  __shared__ unsigned char lb[TILE];
  __shared__ int2 stg[TILE];
  int t = threadIdx.x;
  int base = blockIdx.x * TILE;
  hist[t] = 0;
  __syncthreads();
  int s[16], c[16];
#pragma unroll
  for (int i = 0; i < 16; ++i) {
    int e = base + i * 256 + t;
    if (e < E) {
      s[i] = ei[e];
      c[i] = ei[E + e];
      atomicAdd(&hist[c[i] >> 9], 1);
    } else {
      c[i] = -1;
    }
  }
  __syncthreads();
  int h = hist[t];
  scn[t] = h;
  __syncthreads();
  for (int off = 1; off < 256; off <<= 1) {
    int v = (t >= off) ? scn[t - off] : 0;
    __syncthreads();
    scn[t] += v;
    __syncthreads();
  }
  excl[t] = scn[t] - h;
  gb[t] = (h > 0) ? atomicAdd(&bcur[t], h) : 0;
  __syncthreads();
  hist[t] = excl[t];  // reuse as local placement cursor
  __syncthreads();
#pragma unroll
  for (int i = 0; i < 16; ++i) {
    if (c[i] >= 0) {
      int b = c[i] >> 9;
      int p = atomicAdd(&hist[b], 1);
      stg[p] = make_int2(s[i], c[i]);
      lb[p] = (unsigned char)b;
    }
  }
  __syncthreads();
  int cntE = min(TILE, E - base);
#pragma unroll
  for (int i = 0; i < 16; ++i) {
    int p = i * 256 + t;
    if (p < cntE) {
      int b = lb[p];
      barr[gb[b] + (p - excl[b])] = stg[p];
    }
  }
}

// ---------------- bucket-level exclusive prefix (nbuck <= 256), 1 block ------
__global__ void k_bscan(const int* __restrict__ bcur, int* __restrict__ bstart,
                        int nbuck, int* __restrict__ rowptr, int N, int E) {
  __shared__ int s[256];
  int t = threadIdx.x;
  int v = (t < nbuck) ? (bcur[t] - t * BCAP) : 0;
  s[t] = v;
  __syncthreads();
  for (int off = 1; off < 256; off <<= 1) {
    int tv = (t >= off) ? s[t - off] : 0;
    __syncthreads();
    s[t] += tv;
    __syncthreads();
  }
  if (t < nbuck) bstart[t] = s[t] - v;
  if (t == 0) rowptr[N] = E;
}

// ---------------- pass B: bucket -> CSR; also emits rowptr & dinv ------------
__global__ __launch_bounds__(512) void k_finalize(const int* __restrict__ bcur,
                                                  const int* __restrict__ bstart,
                                                  const int2* __restrict__ barr,
                                                  int* __restrict__ rowptr,
                                                  float* __restrict__ dinv,
                                                  int* __restrict__ ed4, int N) {
  __shared__ int cnt[512];
  __shared__ int sbuf[512];
  __shared__ int cur[512];
  int b = blockIdx.x;
  int node0 = b << 9;
  int nn = min(512, N - node0);
  int t = threadIdx.x;
  cnt[t] = 0;
  __syncthreads();
  int m = bcur[b] - b * BCAP;  // edges in this bucket
  int src = b * BCAP;
  int bst = bstart[b];
  for (int i = t; i < m; i += 512) atomicAdd(&cnt[barr[src + i].y - node0], 1);
  __syncthreads();
  int v = cnt[t];
  sbuf[t] = v;
  __syncthreads();
  for (int off = 1; off < 512; off <<= 1) {
    int tv = (t >= off) ? sbuf[t - off] : 0;
    __syncthreads();
    sbuf[t] += tv;
    __syncthreads();
  }
  int excl = sbuf[t] - v;
  if (t < nn) {
    rowptr[node0 + t] = bst + excl;
    dinv[node0 + t] = rsqrtf((float)v + 1.0f);
  }
  cur[t] = bst + excl;
  __syncthreads();
  for (int i = t; i < m; i += 512) {
    int2 q = barr[src + i];
    int slot = atomicAdd(&cur[q.y - node0], 1);
    ed4[slot] = q.x;
  }
}

// ---------------- W pack: split fp32 W into bf16 hi/lo, MFMA B-frag layout ----
__global__ void k_prep_w(const float* __restrict__ W, short* __restrict__ Whp,
                         short* __restrict__ Wlp) {
  int i = blockIdx.x * 256 + threadIdx.x;  // 0..16383
  int j = i & 7;
  int lane = (i >> 3) & 63;
  int cg = (i >> 9) & 3;
  int kc = i >> 11;
  int k = kc * 32 + (lane >> 4) * 8 + j;
  int col = cg * 16 + (lane & 15);
  float w = W[k * 64 + col];
  unsigned u = __float_as_uint(w);
  unsigned hbits = u & 0xFFFF0000u;  // truncate: residual captured exactly by lo
  Whp[i] = (short)(hbits >> 16);
  Wlp[i] = (short)f2bf(w - __uint_as_float(hbits));
}

// ---------------- h = relu(x @ W1 + b1), split-precision bf16 MFMA -----------
// Block-cooperative: 64 rows/block, K in 4 chunks of 64 cols, LDS double-buffer.
// Staging: fully coalesced global float4 loads (wave covers 16 rows x 256 B
// contiguous) -> ds_write_b128 into padded tile (stride 68 floats: 2-way bank
// aliasing = free). Next chunk's global loads issued BEFORE current compute
// (T14 issue-early), so HBM latency hides under split-VALU + MFMA.
__global__ __launch_bounds__(256) void k_gemm_mfma(const float* __restrict__ x,
                                                   const short* __restrict__ Whp,
                                                   const short* __restrict__ Wlp,
                                                   const float* __restrict__ b,
                                                   const float* __restrict__ dinv,
                                                   float* __restrict__ h,
                                                   bf16_t* __restrict__ hb,
                                                   bf16_t* __restrict__ zs0, int N) {
  __shared__ float xs[2][64 * 68];  // 2 x 17 KB
  int tid = threadIdx.x;
  int wid = tid >> 6;
  int lane = tid & 63;
  long row0b = (long)blockIdx.x * 64;

  // staging assignment: thread t covers floats [ (t&3)*16, +16 ) of row t>>2
  int sfr = tid >> 2;
  int sfo = (tid & 3) * 16;
  long srow = row0b + sfr;
  if (srow >= N) srow = N - 1;  // clamp (stores guarded)
  const float* sp = x + srow * 256 + sfo;

  // compute assignment: wave owns rows [wid*16, +16)
  int rr = lane & 15;
  int q = lane >> 4;
  int lrow = wid * 16 + rr;

  f32x4 g[4];
  // prologue: chunk 0
#pragma unroll
  for (int i = 0; i < 4; ++i) g[i] = *(const f32x4*)(sp + i * 4);
#pragma unroll
  for (int i = 0; i < 4; ++i)
    *(f32x4*)&xs[0][sfr * 68 + sfo + i * 4] = g[i];
  __syncthreads();

  f32x4 acc[4];
#pragma unroll
  for (int cg = 0; cg < 4; ++cg) acc[cg] = (f32x4){0.f, 0.f, 0.f, 0.f};

  int bf = 0;
  for (int c = 0; c < 4; ++c) {
    if (c < 3) {
      const float* spn = sp + (c + 1) * 64;
#pragma unroll
      for (int i = 0; i < 4; ++i) g[i] = *(const f32x4*)(spn + i * 4);
    }
#pragma unroll
    for (int kcl = 0; kcl < 2; ++kcl) {
      int kc = c * 2 + kcl;
      const float* lp = &xs[bf][lrow * 68 + kcl * 32 + q * 8];
      f32x4 a0 = *(const f32x4*)lp;
      f32x4 a1 = *(const f32x4*)(lp + 4);
      float f[8] = {a0.x, a0.y, a0.z, a0.w, a1.x, a1.y, a1.z, a1.w};
      bf16x8 xh, xl;
#pragma unroll
      for (int j = 0; j < 8; ++j) {
        unsigned u = __float_as_uint(f[j]);
        unsigned hbits = u & 0xFFFF0000u;
        xh[j] = (short)(hbits >> 16);
        xl[j] = (short)f2bf(f[j] - __uint_as_float(hbits));
      }
#pragma unroll
      for (int cg = 0; cg < 4; ++cg) {
        const bf16x8 wh = *(const bf16x8*)&Whp[((kc * 4 + cg) * 64 + lane) * 8];
        const bf16x8 wl = *(const bf16x8*)&Wlp[((kc * 4 + cg) * 64 + lane) * 8];
        acc[cg] = __builtin_amdgcn_mfma_f32_16x16x32_bf16(xh, wh, acc[cg], 0, 0, 0);
        acc[cg] = __builtin_amdgcn_mfma_f32_16x16x32_bf16(xl, wh, acc[cg], 0, 0, 0);
        acc[cg] = __builtin_amdgcn_mfma_f32_16x16x32_bf16(xh, wl, acc[cg], 0, 0, 0);
      }
    }
    if (c < 3) {
      // write next chunk into the other buffer: safe, it was last read in
      // chunk c-1 and all waves passed that barrier.
#pragma unroll
      for (int i = 0; i < 4; ++i)
        *(f32x4*)&xs[bf ^ 1][sfr * 68 + sfo + i * 4] = g[i];
    }
    __syncthreads();
    bf ^= 1;
  }

  long rbase = row0b + wid * 16 + q * 4;
  float dv[4];
#pragma unroll
  for (int r = 0; r < 4; ++r) {
    long row = rbase + r;
    dv[r] = (row < N) ? dinv[row] : 0.f;
  }
#pragma unroll
  for (int cg = 0; cg < 4; ++cg) {
    int col = cg * 16 + (lane & 15);
    float bias = b[col];
#pragma unroll
    for (int r = 0; r < 4; ++r) {
      long row = rbase + r;
      if (row < N) {
        float v = fmaxf(acc[cg][r] + bias, 0.f);
        size_t o = (size_t)row * 64 + col;
        h[o] = v;
        hb[o] = f2bf(v);
        zs0[o] = f2bf(dv[r] * v);
      }
    }
  }
}

// ---------------- propagation v4: 8 lanes/node, bf16x8 gathers ---------------
// lane = (g = lane>>3 node sub-index, u = lane&7 channel octet). Per 8 edges:
// one coalesced ed4 load (lane u gets edge off+u), __shfl broadcast within the
// 8-lane group, 8 independent 16B gathers (full 128B row per instr per group).
template <int LAST>
__global__ __launch_bounds__(256) void k_prop(const int* __restrict__ rowptr,
                                              const int* __restrict__ ed4,
                                              const float* __restrict__ dinv,
                                              const bf16_t* __restrict__ zin,
                                              const bf16_t* __restrict__ hbi,
                                              const float* __restrict__ hf,
                                              void* __restrict__ zout_, int N) {
  int tid = threadIdx.x;
  int lane = tid & 63;
  int u = lane & 7;       // channel octet: channels u*8 .. u*8+7
  int g = lane >> 3;      // node sub-index within wave (0..7)
  int gbase = lane & 56;  // first lane of this group
  int node = blockIdx.x * 32 + (tid >> 6) * 8 + g;
  bool live = node < N;
  if (!live) node = N - 1;  // clamp; stores guarded
  int beg = rowptr[node];
  int m = rowptr[node + 1] - beg;
  float dvc = dinv[node];
  size_t base = (size_t)node * 64 + u * 8;

  union V { bf16x8 v; unsigned d[4]; };
  V zs;
  zs.v = *(const bf16x8*)(zin + base);  // self term (already dinv-scaled)
  float a0 = __uint_as_float(zs.d[0] << 16);
  float a1 = __uint_as_float(zs.d[0] & 0xFFFF0000u);
  float a2 = __uint_as_float(zs.d[1] << 16);
  float a3 = __uint_as_float(zs.d[1] & 0xFFFF0000u);
  float a4 = __uint_as_float(zs.d[2] << 16);
  float a5 = __uint_as_float(zs.d[2] & 0xFFFF0000u);
  float a6 = __uint_as_float(zs.d[3] << 16);
  float a7 = __uint_as_float(zs.d[3] & 0xFFFF0000u);

  int full = m & ~7;
  for (int off = 0; off < full; off += 8) {
    int ev = ed4[beg + off + u];
#pragma unroll
    for (int j = 0; j < 8; ++j) {
      int src = __shfl(ev, gbase + j, 64);
      V z;
      z.v = *(const bf16x8*)(zin + (size_t)src * 64 + u * 8);
      a0 += __uint_as_float(z.d[0] << 16);
      a1 += __uint_as_float(z.d[0] & 0xFFFF0000u);
      a2 += __uint_as_float(z.d[1] << 16);
      a3 += __uint_as_float(z.d[1] & 0xFFFF0000u);
      a4 += __uint_as_float(z.d[2] << 16);
      a5 += __uint_as_float(z.d[2] & 0xFFFF0000u);
      a6 += __uint_as_float(z.d[3] << 16);
      a7 += __uint_as_float(z.d[3] & 0xFFFF0000u);
    }
  }
  int rem = m - full;
  if (rem > 0) {
    int ev = (u < rem) ? ed4[beg + full + u] : 0;
    for (int j = 0; j < rem; ++j) {
      int src = __shfl(ev, gbase + j, 64);
      V z;
      z.v = *(const bf16x8*)(zin + (size_t)src * 64 + u * 8);
      a0 += __uint_as_float(z.d[0] << 16);
      a1 += __uint_as_float(z.d[0] & 0xFFFF0000u);
      a2 += __uint_as_float(z.d[1] << 16);
      a3 += __uint_as_float(z.d[1] & 0xFFFF0000u);
      a4 += __uint_as_float(z.d[2] << 16);
      a5 += __uint_as_float(z.d[2] & 0xFFFF0000u);
      a6 += __uint_as_float(z.d[3] << 16);
      a7 += __uint_as_float(z.d[3] & 0xFFFF0000u);
    }
  }

  float sca = 0.9f * dvc;
  if (LAST) {
    const float* hp = hf + base;
    f32x4 h0 = *(const f32x4*)hp;
    f32x4 h1 = *(const f32x4*)(hp + 4);
    f32x4 r0, r1;
    r0.x = sca * a0 + 0.1f * h0.x;
    r0.y = sca * a1 + 0.1f * h0.y;
    r0.z = sca * a2 + 0.1f * h0.z;
    r0.w = sca * a3 + 0.1f * h0.w;
    r1.x = sca * a4 + 0.1f * h1.x;
    r1.y = sca * a5 + 0.1f * h1.y;
    r1.z = sca * a6 + 0.1f * h1.z;
    r1.w = sca * a7 + 0.1f * h1.w;
    if (live) {
      float* zp = (float*)zout_ + base;
      *(f32x4*)zp = r0;
      *(f32x4*)(zp + 4) = r1;
    }
  } else {
    V hv;
    hv.v = *(const bf16x8*)(hbi + base);
    float r0 = dvc * (sca * a0 + 0.1f * __uint_as_float(hv.d[0] << 16));
    float r1 = dvc * (sca * a1 + 0.1f * __uint_as_float(hv.d[0] & 0xFFFF0000u));
    float r2 = dvc * (sca * a2 + 0.1f * __uint_as_float(hv.d[1] << 16));
    float r3 = dvc * (sca * a3 + 0.1f * __uint_as_float(hv.d[1] & 0xFFFF0000u));
    float r4 = dvc * (sca * a4 + 0.1f * __uint_as_float(hv.d[2] << 16));
    float r5 = dvc * (sca * a5 + 0.1f * __uint_as_float(hv.d[2] & 0xFFFF0000u));
    float r6 = dvc * (sca * a6 + 0.1f * __uint_as_float(hv.d[3] << 16));
    float r7 = dvc * (sca * a7 + 0.1f * __uint_as_float(hv.d[3] & 0xFFFF0000u));
    uint4 o;
    o.x = (unsigned)f2bf(r0) | (((unsigned)f2bf(r1)) << 16);
    o.y = (unsigned)f2bf(r2) | (((unsigned)f2bf(r3)) << 16);
    o.z = (unsigned)f2bf(r4) | (((unsigned)f2bf(r5)) << 16);
    o.w = (unsigned)f2bf(r6) | (((unsigned)f2bf(r7)) << 16);
    if (live) *(uint4*)((bf16_t*)zout_ + base) = o;
  }
}

// ---------------- launch ----------------

extern "C" void kernel_launch(void* const* d_in, const int* in_sizes, int n_in,
                              void* d_out, int out_size, void* d_ws, size_t ws_size,
                              hipStream_t stream) {
  const float* x = (const float*)d_in[0];
  const int* ei = (const int*)d_in[1];  // int32 per harness contract
  const float* W1 = (const float*)d_in[2];
  const float* b1 = (const float*)d_in[3];
  float* zfinal = (float*)d_out;

  int OUT = in_sizes[3];        // 64
  int IN = in_sizes[2] / OUT;   // 256
  int N = in_sizes[0] / IN;     // 100000
  int E = in_sizes[1] / 2;      // 1600000

  char* ws = (char*)d_ws;
  size_t off = 0;
  auto alloc = [&](size_t bytes) -> char* {
    char* p = ws + off;
    off = (off + bytes + 255) & ~(size_t)255;
    return p;
  };
  int nbuck = (N + 511) >> 9;  // 196
  float* h = (float*)alloc((size_t)N * OUT * 4);       // 25.6 MB
  bf16_t* hb = (bf16_t*)alloc((size_t)N * OUT * 2);    // 12.8 MB
  bf16_t* zs0 = (bf16_t*)alloc((size_t)N * OUT * 2);   // 12.8 MB
  bf16_t* z0 = (bf16_t*)alloc((size_t)N * OUT * 2);    // 12.8 MB
  bf16_t* z1 = (bf16_t*)alloc((size_t)N * OUT * 2);    // 12.8 MB
  int2* barr = (int2*)alloc((size_t)nbuck * BCAP * 8); // 25.7 MB
  int* ed4 = (int*)alloc((size_t)E * 4 + 64);          // 6.4 MB
  short* Whp = (short*)alloc(16384 * 2);
  short* Wlp = (short*)alloc(16384 * 2);
  int* rowptr = (int*)alloc((size_t)(N + 1) * 4);
  float* dinv = (float*)alloc((size_t)N * 4);
  int* bcur = (int*)alloc(256 * 4);
  int* bstart = (int*)alloc(256 * 4);
  (void)ws_size;

  hipLaunchKernelGGL(k_initb, dim3(1), dim3(256), 0, stream, bcur, nbuck);
  hipLaunchKernelGGL(k_bucket, dim3((E + TILE - 1) / TILE), dim3(256), 0, stream, ei, E,
                     bcur, barr);
  hipLaunchKernelGGL(k_bscan, dim3(1), dim3(256), 0, stream, bcur, bstart, nbuck, rowptr,
                     N, E);
  hipLaunchKernelGGL(k_finalize, dim3(nbuck), dim3(512), 0, stream, bcur, bstart, barr,
                     rowptr, dinv, ed4, N);
  hipLaunchKernelGGL(k_prep_w, dim3(64), dim3(256), 0, stream, W1, Whp, Wlp);
  hipLaunchKernelGGL(k_gemm_mfma, dim3((N + 63) / 64), dim3(256), 0, stream, x, Whp,
                     Wlp, b1, dinv, h, hb, zs0, N);

  dim3 pgrid((N + 31) / 32);  // 256 threads = 4 waves x 8 nodes = 32 nodes/block
  const bf16_t* zi = zs0;
  bf16_t* zb[2] = {z0, z1};
  for (int it = 0; it < KITER - 1; ++it) {
    bf16_t* zo = zb[it & 1];
    hipLaunchKernelGGL((k_prop<0>), pgrid, dim3(256), 0, stream, rowptr, ed4, dinv, zi,
                       hb, h, (void*)zo, N);
    zi = zo;
  }
  hipLaunchKernelGGL((k_prop<1>), pgrid, dim3(256), 0, stream, rowptr, ed4, dinv, zi, hb,
                     h, (void*)zfinal, N);
}

// Round 5
// 414.589 us; speedup vs baseline: 1.5650x; 1.0224x over previous
//
#include <hip/hip_runtime.h>

#define KITER 10
#define TILE 4096
#define BCAP 16384  // bucket staging capacity (expected 8192/bucket, +90 sigma)
typedef unsigned short bf16_t;
typedef __attribute__((ext_vector_type(4))) short bf16x4;
typedef __attribute__((ext_vector_type(8))) short bf16x8;
typedef __attribute__((ext_vector_type(4))) float f32x4;

__device__ __forceinline__ float bf2f(bf16_t u) {
  union { unsigned u; float f; } cv;
  cv.u = ((unsigned)u) << 16;
  return cv.f;
}
__device__ __forceinline__ bf16_t f2bf(float f) {
  unsigned u = __float_as_uint(f);
  unsigned r = (u + 0x7FFFu + ((u >> 16) & 1u)) >> 16;  // round-nearest-even
  return (bf16_t)r;
}

// ---------------- bucket cursor init: bcur[b] = b*BCAP ----------------
__global__ void k_initb(int* __restrict__ bcur, int nbuck) {
  int i = threadIdx.x;
  if (i < nbuck) bcur[i] = i * BCAP;
}

// ---------------- bucket sort pass A: tile -> per-bucket coalesced runs ------
__global__ __launch_bounds__(256) void k_bucket(const int* __restrict__ ei, int E,
                                                int* __restrict__ bcur,
                                                int2* __restrict__ barr) {
  __shared__ int hist[256];
  __shared__ int scn[256];
  __shared__ int excl[256];
  __shared__ int gb[256];
  __shared__ unsigned char lb[TILE];
  __shared__ int2 stg[TILE];
  int t = threadIdx.x;
  int base = blockIdx.x * TILE;
  hist[t] = 0;
  __syncthreads();
  int s[16], c[16];
#pragma unroll
  for (int i = 0; i < 16; ++i) {
    int e = base + i * 256 + t;
    if (e < E) {
      s[i] = ei[e];
      c[i] = ei[E + e];
      atomicAdd(&hist[c[i] >> 9], 1);
    } else {
      c[i] = -1;
    }
  }
  __syncthreads();
  int h = hist[t];
  scn[t] = h;
  __syncthreads();
  for (int off = 1; off < 256; off <<= 1) {
    int v = (t >= off) ? scn[t - off] : 0;
    __syncthreads();
    scn[t] += v;
    __syncthreads();
  }
  excl[t] = scn[t] - h;
  gb[t] = (h > 0) ? atomicAdd(&bcur[t], h) : 0;
  __syncthreads();
  hist[t] = excl[t];  // reuse as local placement cursor
  __syncthreads();
#pragma unroll
  for (int i = 0; i < 16; ++i) {
    if (c[i] >= 0) {
      int b = c[i] >> 9;
      int p = atomicAdd(&hist[b], 1);
      stg[p] = make_int2(s[i], c[i]);
      lb[p] = (unsigned char)b;
    }
  }
  __syncthreads();
  int cntE = min(TILE, E - base);
#pragma unroll
  for (int i = 0; i < 16; ++i) {
    int p = i * 256 + t;
    if (p < cntE) {
      int b = lb[p];
      barr[gb[b] + (p - excl[b])] = stg[p];
    }
  }
}

// ---------------- bucket-level exclusive prefix (nbuck <= 256), 1 block ------
__global__ void k_bscan(const int* __restrict__ bcur, int* __restrict__ bstart,
                        int nbuck, int* __restrict__ rowptr, int N, int E) {
  __shared__ int s[256];
  int t = threadIdx.x;
  int v = (t < nbuck) ? (bcur[t] - t * BCAP) : 0;
  s[t] = v;
  __syncthreads();
  for (int off = 1; off < 256; off <<= 1) {
    int tv = (t >= off) ? s[t - off] : 0;
    __syncthreads();
    s[t] += tv;
    __syncthreads();
  }
  if (t < nbuck) bstart[t] = s[t] - v;
  if (t == 0) rowptr[N] = E;
}

// ---------------- pass B: bucket -> CSR; also emits rowptr & dinv ------------
__global__ __launch_bounds__(512) void k_finalize(const int* __restrict__ bcur,
                                                  const int* __restrict__ bstart,
                                                  const int2* __restrict__ barr,
                                                  int* __restrict__ rowptr,
                                                  float* __restrict__ dinv,
                                                  int* __restrict__ ed4, int N) {
  __shared__ int cnt[512];
  __shared__ int sbuf[512];
  __shared__ int cur[512];
  int b = blockIdx.x;
  int node0 = b << 9;
  int nn = min(512, N - node0);
  int t = threadIdx.x;
  cnt[t] = 0;
  __syncthreads();
  int m = bcur[b] - b * BCAP;  // edges in this bucket
  int src = b * BCAP;
  int bst = bstart[b];
  for (int i = t; i < m; i += 512) atomicAdd(&cnt[barr[src + i].y - node0], 1);
  __syncthreads();
  int v = cnt[t];
  sbuf[t] = v;
  __syncthreads();
  for (int off = 1; off < 512; off <<= 1) {
    int tv = (t >= off) ? sbuf[t - off] : 0;
    __syncthreads();
    sbuf[t] += tv;
    __syncthreads();
  }
  int excl = sbuf[t] - v;
  if (t < nn) {
    rowptr[node0 + t] = bst + excl;
    dinv[node0 + t] = rsqrtf((float)v + 1.0f);
  }
  cur[t] = bst + excl;
  __syncthreads();
  for (int i = t; i < m; i += 512) {
    int2 q = barr[src + i];
    int slot = atomicAdd(&cur[q.y - node0], 1);
    ed4[slot] = q.x;
  }
}

// ---------------- W pack: split fp32 W into bf16 hi/lo, MFMA B-frag layout ----
__global__ void k_prep_w(const float* __restrict__ W, short* __restrict__ Whp,
                         short* __restrict__ Wlp) {
  int i = blockIdx.x * 256 + threadIdx.x;  // 0..16383
  int j = i & 7;
  int lane = (i >> 3) & 63;
  int cg = (i >> 9) & 3;
  int kc = i >> 11;
  int k = kc * 32 + (lane >> 4) * 8 + j;
  int col = cg * 16 + (lane & 15);
  float w = W[k * 64 + col];
  unsigned u = __float_as_uint(w);
  unsigned hbits = u & 0xFFFF0000u;  // truncate: residual captured exactly by lo
  Whp[i] = (short)(hbits >> 16);
  Wlp[i] = (short)f2bf(w - __uint_as_float(hbits));
}

// ---------------- h = relu(x @ W1 + b1), split-precision bf16 MFMA -----------
// Round-2 compute structure (512 thr = 8 waves, W hi/lo staged in LDS, full x
// reg prefetch) + NEW epilogue: bias+relu in-register, C-tile staged into LDS
// (reusing W buffer post-compute, stride 68 = 2-way bank aliasing, free), then
// FULLY COALESCED full-line writeout: thread t owns (row t>>2, quarter t&3) ->
// h 64 B/thread, hb/zs0 2x16 B packed stores. No partial-sector writes.
__global__ __launch_bounds__(512) void k_gemm_mfma(const float* __restrict__ x,
                                                   const short* __restrict__ Whp,
                                                   const short* __restrict__ Wlp,
                                                   const float* __restrict__ b,
                                                   const float* __restrict__ dinv,
                                                   float* __restrict__ h,
                                                   bf16_t* __restrict__ hb,
                                                   bf16_t* __restrict__ zs0, int N) {
  __shared__ __align__(16) char smem[65536];
  short* WhS = (short*)smem;             // 32 KB
  short* WlS = (short*)(smem + 32768);   // 32 KB
  float* Cst = (float*)smem;             // reused post-compute: 128 x 68 floats
  int tid = threadIdx.x;
  for (int i = tid; i < 2048; i += 512) {
    ((int4*)WhS)[i] = ((const int4*)Whp)[i];
    ((int4*)WlS)[i] = ((const int4*)Wlp)[i];
  }
  __syncthreads();
  int wid = tid >> 6;
  int lane = tid & 63;
  int rr = lane & 15;
  int q = lane >> 4;
  long row0 = (long)blockIdx.x * 128 + wid * 16;
  long arow = row0 + rr;
  if (arow > N - 1) arow = N - 1;  // clamp (stores guarded)
  const float* xr = x + arow * 256 + q * 8;

  // prefetch whole row slice: 8 kchunks x 8 floats
  f32x4 xa[8], xb[8];
#pragma unroll
  for (int kc = 0; kc < 8; ++kc) {
    xa[kc] = *(const f32x4*)(xr + kc * 32);
    xb[kc] = *(const f32x4*)(xr + kc * 32 + 4);
  }

  f32x4 acc[4];
#pragma unroll
  for (int cg = 0; cg < 4; ++cg) acc[cg] = (f32x4){0.f, 0.f, 0.f, 0.f};

#pragma unroll
  for (int kc = 0; kc < 8; ++kc) {
    float f[8] = {xa[kc].x, xa[kc].y, xa[kc].z, xa[kc].w,
                  xb[kc].x, xb[kc].y, xb[kc].z, xb[kc].w};
    bf16x8 xh, xl;
#pragma unroll
    for (int j = 0; j < 8; ++j) {
      unsigned u = __float_as_uint(f[j]);
      unsigned hbits = u & 0xFFFF0000u;
      xh[j] = (short)(hbits >> 16);
      xl[j] = (short)f2bf(f[j] - __uint_as_float(hbits));
    }
#pragma unroll
    for (int cg = 0; cg < 4; ++cg) {
      const bf16x8 wh = *(const bf16x8*)&WhS[((kc * 4 + cg) * 64 + lane) * 8];
      const bf16x8 wl = *(const bf16x8*)&WlS[((kc * 4 + cg) * 64 + lane) * 8];
      acc[cg] = __builtin_amdgcn_mfma_f32_16x16x32_bf16(xh, wh, acc[cg], 0, 0, 0);
      acc[cg] = __builtin_amdgcn_mfma_f32_16x16x32_bf16(xl, wh, acc[cg], 0, 0, 0);
      acc[cg] = __builtin_amdgcn_mfma_f32_16x16x32_bf16(xh, wl, acc[cg], 0, 0, 0);
    }
  }

  // -------- epilogue: bias+relu in-reg, stage C tile to LDS (W is dead) -----
  __syncthreads();  // all waves finished reading WhS/WlS
#pragma unroll
  for (int cg = 0; cg < 4; ++cg) {
    float bias = b[cg * 16 + rr];
#pragma unroll
    for (int r = 0; r < 4; ++r) {
      float v = fmaxf(acc[cg][r] + bias, 0.f);
      Cst[(wid * 16 + q * 4 + r) * 68 + cg * 16 + rr] = v;
    }
  }
  __syncthreads();

  // -------- coalesced writeout: thread t -> row t>>2, col quarter t&3 -------
  int lrow = tid >> 2;
  int cq = tid & 3;
  long grow = (long)blockIdx.x * 128 + lrow;
  if (grow < N) {
    union F4U { f32x4 v; float f[4]; };
    const float* cp = &Cst[lrow * 68 + cq * 16];
    F4U w0, w1, w2, w3;
    w0.v = *(const f32x4*)cp;
    w1.v = *(const f32x4*)(cp + 4);
    w2.v = *(const f32x4*)(cp + 8);
    w3.v = *(const f32x4*)(cp + 12);
    size_t ob = (size_t)grow * 64 + cq * 16;
    float* hp = h + ob;
    *(f32x4*)hp = w0.v;
    *(f32x4*)(hp + 4) = w1.v;
    *(f32x4*)(hp + 8) = w2.v;
    *(f32x4*)(hp + 12) = w3.v;
    float dv = dinv[grow];
    uint4 ub, ub2, uz, uz2;
    ub.x = (unsigned)f2bf(w0.f[0]) | ((unsigned)f2bf(w0.f[1]) << 16);
    ub.y = (unsigned)f2bf(w0.f[2]) | ((unsigned)f2bf(w0.f[3]) << 16);
    ub.z = (unsigned)f2bf(w1.f[0]) | ((unsigned)f2bf(w1.f[1]) << 16);
    ub.w = (unsigned)f2bf(w1.f[2]) | ((unsigned)f2bf(w1.f[3]) << 16);
    ub2.x = (unsigned)f2bf(w2.f[0]) | ((unsigned)f2bf(w2.f[1]) << 16);
    ub2.y = (unsigned)f2bf(w2.f[2]) | ((unsigned)f2bf(w2.f[3]) << 16);
    ub2.z = (unsigned)f2bf(w3.f[0]) | ((unsigned)f2bf(w3.f[1]) << 16);
    ub2.w = (unsigned)f2bf(w3.f[2]) | ((unsigned)f2bf(w3.f[3]) << 16);
    uz.x = (unsigned)f2bf(dv * w0.f[0]) | ((unsigned)f2bf(dv * w0.f[1]) << 16);
    uz.y = (unsigned)f2bf(dv * w0.f[2]) | ((unsigned)f2bf(dv * w0.f[3]) << 16);
    uz.z = (unsigned)f2bf(dv * w1.f[0]) | ((unsigned)f2bf(dv * w1.f[1]) << 16);
    uz.w = (unsigned)f2bf(dv * w1.f[2]) | ((unsigned)f2bf(dv * w1.f[3]) << 16);
    uz2.x = (unsigned)f2bf(dv * w2.f[0]) | ((unsigned)f2bf(dv * w2.f[1]) << 16);
    uz2.y = (unsigned)f2bf(dv * w2.f[2]) | ((unsigned)f2bf(dv * w2.f[3]) << 16);
    uz2.z = (unsigned)f2bf(dv * w3.f[0]) | ((unsigned)f2bf(dv * w3.f[1]) << 16);
    uz2.w = (unsigned)f2bf(dv * w3.f[2]) | ((unsigned)f2bf(dv * w3.f[3]) << 16);
    *(uint4*)(hb + ob) = ub;
    *(uint4*)(hb + ob + 8) = ub2;
    *(uint4*)(zs0 + ob) = uz;
    *(uint4*)(zs0 + ob + 8) = uz2;
  }
}

// ---------------- propagation: 8 lanes/node, bf16x8 gathers ------------------
template <int LAST>
__global__ __launch_bounds__(256) void k_prop(const int* __restrict__ rowptr,
                                              const int* __restrict__ ed4,
                                              const float* __restrict__ dinv,
                                              const bf16_t* __restrict__ zin,
                                              const bf16_t* __restrict__ hbi,
                                              const float* __restrict__ hf,
                                              void* __restrict__ zout_, int N) {
  int tid = threadIdx.x;
  int lane = tid & 63;
  int u = lane & 7;       // channel octet: channels u*8 .. u*8+7
  int g = lane >> 3;      // node sub-index within wave (0..7)
  int gbase = lane & 56;  // first lane of this group
  int node = blockIdx.x * 32 + (tid >> 6) * 8 + g;
  bool live = node < N;
  if (!live) node = N - 1;  // clamp; stores guarded
  int beg = rowptr[node];
  int m = rowptr[node + 1] - beg;
  float dvc = dinv[node];
  size_t base = (size_t)node * 64 + u * 8;

  union V { bf16x8 v; unsigned d[4]; };
  V zs;
  zs.v = *(const bf16x8*)(zin + base);  // self term (already dinv-scaled)
  float a0 = __uint_as_float(zs.d[0] << 16);
  float a1 = __uint_as_float(zs.d[0] & 0xFFFF0000u);
  float a2 = __uint_as_float(zs.d[1] << 16);
  float a3 = __uint_as_float(zs.d[1] & 0xFFFF0000u);
  float a4 = __uint_as_float(zs.d[2] << 16);
  float a5 = __uint_as_float(zs.d[2] & 0xFFFF0000u);
  float a6 = __uint_as_float(zs.d[3] << 16);
  float a7 = __uint_as_float(zs.d[3] & 0xFFFF0000u);

  int full = m & ~7;
  for (int off = 0; off < full; off += 8) {
    int ev = ed4[beg + off + u];
#pragma unroll
    for (int j = 0; j < 8; ++j) {
      int src = __shfl(ev, gbase + j, 64);
      V z;
      z.v = *(const bf16x8*)(zin + (size_t)src * 64 + u * 8);
      a0 += __uint_as_float(z.d[0] << 16);
      a1 += __uint_as_float(z.d[0] & 0xFFFF0000u);
      a2 += __uint_as_float(z.d[1] << 16);
      a3 += __uint_as_float(z.d[1] & 0xFFFF0000u);
      a4 += __uint_as_float(z.d[2] << 16);
      a5 += __uint_as_float(z.d[2] & 0xFFFF0000u);
      a6 += __uint_as_float(z.d[3] << 16);
      a7 += __uint_as_float(z.d[3] & 0xFFFF0000u);
    }
  }
  int rem = m - full;
  if (rem > 0) {
    int ev = (u < rem) ? ed4[beg + full + u] : 0;
    for (int j = 0; j < rem; ++j) {
      int src = __shfl(ev, gbase + j, 64);
      V z;
      z.v = *(const bf16x8*)(zin + (size_t)src * 64 + u * 8);
      a0 += __uint_as_float(z.d[0] << 16);
      a1 += __uint_as_float(z.d[0] & 0xFFFF0000u);
      a2 += __uint_as_float(z.d[1] << 16);
      a3 += __uint_as_float(z.d[1] & 0xFFFF0000u);
      a4 += __uint_as_float(z.d[2] << 16);
      a5 += __uint_as_float(z.d[2] & 0xFFFF0000u);
      a6 += __uint_as_float(z.d[3] << 16);
      a7 += __uint_as_float(z.d[3] & 0xFFFF0000u);
    }
  }

  float sca = 0.9f * dvc;
  if (LAST) {
    const float* hp = hf + base;
    f32x4 h0 = *(const f32x4*)hp;
    f32x4 h1 = *(const f32x4*)(hp + 4);
    f32x4 r0, r1;
    r0.x = sca * a0 + 0.1f * h0.x;
    r0.y = sca * a1 + 0.1f * h0.y;
    r0.z = sca * a2 + 0.1f * h0.z;
    r0.w = sca * a3 + 0.1f * h0.w;
    r1.x = sca * a4 + 0.1f * h1.x;
    r1.y = sca * a5 + 0.1f * h1.y;
    r1.z = sca * a6 + 0.1f * h1.z;
    r1.w = sca * a7 + 0.1f * h1.w;
    if (live) {
      float* zp = (float*)zout_ + base;
      *(f32x4*)zp = r0;
      *(f32x4*)(zp + 4) = r1;
    }
  } else {
    V hv;
    hv.v = *(const bf16x8*)(hbi + base);
    float r0 = dvc * (sca * a0 + 0.1f * __uint_as_float(hv.d[0] << 16));
    float r1 = dvc * (sca * a1 + 0.1f * __uint_as_float(hv.d[0] & 0xFFFF0000u));
    float r2 = dvc * (sca * a2 + 0.1f * __uint_as_float(hv.d[1] << 16));
    float r3 = dvc * (sca * a3 + 0.1f * __uint_as_float(hv.d[1] & 0xFFFF0000u));
    float r4 = dvc * (sca * a4 + 0.1f * __uint_as_float(hv.d[2] << 16));
    float r5 = dvc * (sca * a5 + 0.1f * __uint_as_float(hv.d[2] & 0xFFFF0000u));
    float r6 = dvc * (sca * a6 + 0.1f * __uint_as_float(hv.d[3] << 16));
    float r7 = dvc * (sca * a7 + 0.1f * __uint_as_float(hv.d[3] & 0xFFFF0000u));
    uint4 o;
    o.x = (unsigned)f2bf(r0) | (((unsigned)f2bf(r1)) << 16);
    o.y = (unsigned)f2bf(r2) | (((unsigned)f2bf(r3)) << 16);
    o.z = (unsigned)f2bf(r4) | (((unsigned)f2bf(r5)) << 16);
    o.w = (unsigned)f2bf(r6) | (((unsigned)f2bf(r7)) << 16);
    if (live) *(uint4*)((bf16_t*)zout_ + base) = o;
  }
}

// ---------------- launch ----------------

extern "C" void kernel_launch(void* const* d_in, const int* in_sizes, int n_in,
                              void* d_out, int out_size, void* d_ws, size_t ws_size,
                              hipStream_t stream) {
  const float* x = (const float*)d_in[0];
  const int* ei = (const int*)d_in[1];  // int32 per harness contract
  const float* W1 = (const float*)d_in[2];
  const float* b1 = (const float*)d_in[3];
  float* zfinal = (float*)d_out;

  int OUT = in_sizes[3];        // 64
  int IN = in_sizes[2] / OUT;   // 256
  int N = in_sizes[0] / IN;     // 100000
  int E = in_sizes[1] / 2;      // 1600000

  char* ws = (char*)d_ws;
  size_t off = 0;
  auto alloc = [&](size_t bytes) -> char* {
    char* p = ws + off;
    off = (off + bytes + 255) & ~(size_t)255;
    return p;
  };
  int nbuck = (N + 511) >> 9;  // 196
  float* h = (float*)alloc((size_t)N * OUT * 4);       // 25.6 MB
  bf16_t* hb = (bf16_t*)alloc((size_t)N * OUT * 2);    // 12.8 MB
  bf16_t* zs0 = (bf16_t*)alloc((size_t)N * OUT * 2);   // 12.8 MB
  bf16_t* z0 = (bf16_t*)alloc((size_t)N * OUT * 2);    // 12.8 MB
  bf16_t* z1 = (bf16_t*)alloc((size_t)N * OUT * 2);    // 12.8 MB
  int2* barr = (int2*)alloc((size_t)nbuck * BCAP * 8); // 25.7 MB
  int* ed4 = (int*)alloc((size_t)E * 4 + 64);          // 6.4 MB
  short* Whp = (short*)alloc(16384 * 2);
  short* Wlp = (short*)alloc(16384 * 2);
  int* rowptr = (int*)alloc((size_t)(N + 1) * 4);
  float* dinv = (float*)alloc((size_t)N * 4);
  int* bcur = (int*)alloc(256 * 4);
  int* bstart = (int*)alloc(256 * 4);
  (void)ws_size;

  hipLaunchKernelGGL(k_initb, dim3(1), dim3(256), 0, stream, bcur, nbuck);
  hipLaunchKernelGGL(k_bucket, dim3((E + TILE - 1) / TILE), dim3(256), 0, stream, ei, E,
                     bcur, barr);
  hipLaunchKernelGGL(k_bscan, dim3(1), dim3(256), 0, stream, bcur, bstart, nbuck, rowptr,
                     N, E);
  hipLaunchKernelGGL(k_finalize, dim3(nbuck), dim3(512), 0, stream, bcur, bstart, barr,
                     rowptr, dinv, ed4, N);
  hipLaunchKernelGGL(k_prep_w, dim3(64), dim3(256), 0, stream, W1, Whp, Wlp);
  hipLaunchKernelGGL(k_gemm_mfma, dim3((N + 127) / 128), dim3(512), 0, stream, x, Whp,
                     Wlp, b1, dinv, h, hb, zs0, N);

  dim3 pgrid((N + 31) / 32);  // 256 threads = 4 waves x 8 nodes = 32 nodes/block
  const bf16_t* zi = zs0;
  bf16_t* zb[2] = {z0, z1};
  for (int it = 0; it < KITER - 1; ++it) {
    bf16_t* zo = zb[it & 1];
    hipLaunchKernelGGL((k_prop<0>), pgrid, dim3(256), 0, stream, rowptr, ed4, dinv, zi,
                       hb, h, (void*)zo, N);
    zi = zo;
  }
  hipLaunchKernelGGL((k_prop<1>), pgrid, dim3(256), 0, stream, rowptr, ed4, dinv, zi, hb,
                     h, (void*)zfinal, N);
}